// Round 2
// baseline (4862.136 us; speedup 1.0000x reference)
//
#include <hip/hip_runtime.h>
#include <cstdint>

#define NB 4       // batch
#define TT 8       // timesteps
#define NN 10000   // nodes
#define FIN 128
#define HID 128
#define EE 320000  // edges per timestep (before self-loops)
#define DMODEL 256 // HEADS*HID
#define NEG 0.2f

__device__ __forceinline__ float leaky(float x){ return x >= 0.f ? x : NEG*x; }

// ---------------- CSR build (counting sort by dst, per t) ----------------
__global__ void hist_kernel(const int* __restrict__ eidx, int* __restrict__ counts){
  int idx = blockIdx.x*256 + threadIdx.x;        // t*EE + e, grid exactly T*E/256
  int t = idx / EE, e = idx - t*EE;
  int dst = eidx[(size_t)t*2*EE + EE + e];
  atomicAdd(&counts[t*NN + dst], 1);
}

__global__ void scan_kernel(const int* __restrict__ counts, int* __restrict__ rp,
                            int* __restrict__ cursor){
  int t = blockIdx.x; int tid = threadIdx.x;
  __shared__ int lds[256];
  const int CH = 40;                              // ceil(10000/256)
  int lo = tid*CH, hi = lo+CH < NN ? lo+CH : NN;
  int s = 0;
  for (int i = lo; i < hi; ++i) s += counts[t*NN + i];
  lds[tid] = s; __syncthreads();
  for (int off = 1; off < 256; off <<= 1){
    int v = (tid >= off) ? lds[tid-off] : 0; __syncthreads();
    lds[tid] += v; __syncthreads();
  }
  int run = (tid == 0) ? 0 : lds[tid-1];
  for (int i = lo; i < hi; ++i){
    rp[t*(NN+1) + i] = run; cursor[t*NN + i] = run; run += counts[t*NN + i];
  }
  if (tid == 255) rp[t*(NN+1) + NN] = lds[255];
}

__global__ void scatter_kernel(const int* __restrict__ eidx, int* __restrict__ cursor,
                               int* __restrict__ ssrc){
  int idx = blockIdx.x*256 + threadIdx.x;
  int t = idx / EE, e = idx - t*EE;
  int src = eidx[(size_t)t*2*EE + e];
  int dst = eidx[(size_t)t*2*EE + EE + e];
  int pos = atomicAdd(&cursor[t*NN + dst], 1);
  ssrc[(size_t)t*EE + pos] = src;
}

// ---------------- fp32 tiled GEMM: C[M][256] = A @ W[K][256] ----------------
// Row r of A lives at A + (r/NN)*bstride + (r%NN)*K  (handles x_seq's [B,T,N,F] layout)
template<int K>
__global__ __launch_bounds__(256) void gemm_kernel(const float* __restrict__ A, size_t bstride,
                                                   const float* __restrict__ W,
                                                   float* __restrict__ C){
  __shared__ float As[16][68];   // transposed A tile, padded stride (bank-conflict-free)
  __shared__ float Bs[16][64];
  int tid = threadIdx.x;
  int r0 = blockIdx.x*64, c0 = blockIdx.y*64;
  int lr = tid >> 2, lq = tid & 3;               // A loader: row, float4-slot
  int r = r0 + lr; int b = r / NN; int n = r - b*NN;
  const float* arow = A + (size_t)b*bstride + (size_t)n*K;
  int bk = tid >> 4, bq = tid & 15;              // B loader: k-row, float4-col
  const float* brow = W + (size_t)bk*DMODEL + c0 + bq*4;
  int ty = tid >> 4, tx = tid & 15;
  float acc[4][4];
  #pragma unroll
  for (int i = 0; i < 4; ++i)
    #pragma unroll
    for (int j = 0; j < 4; ++j) acc[i][j] = 0.f;

  for (int k0 = 0; k0 < K; k0 += 16){
    float4 av = *(const float4*)(arow + k0 + lq*4);
    float4 bv = *(const float4*)(brow + (size_t)k0*DMODEL);
    As[lq*4+0][lr] = av.x; As[lq*4+1][lr] = av.y;
    As[lq*4+2][lr] = av.z; As[lq*4+3][lr] = av.w;
    *(float4*)&Bs[bk][bq*4] = bv;
    __syncthreads();
    #pragma unroll
    for (int kk = 0; kk < 16; ++kk){
      float4 a4 = *(const float4*)&As[kk][ty*4];
      float4 b4 = *(const float4*)&Bs[kk][tx*4];
      acc[0][0] += a4.x*b4.x; acc[0][1] += a4.x*b4.y; acc[0][2] += a4.x*b4.z; acc[0][3] += a4.x*b4.w;
      acc[1][0] += a4.y*b4.x; acc[1][1] += a4.y*b4.y; acc[1][2] += a4.y*b4.z; acc[1][3] += a4.y*b4.w;
      acc[2][0] += a4.z*b4.x; acc[2][1] += a4.z*b4.y; acc[2][2] += a4.z*b4.z; acc[2][3] += a4.z*b4.w;
      acc[3][0] += a4.w*b4.x; acc[3][1] += a4.w*b4.y; acc[3][2] += a4.w*b4.z; acc[3][3] += a4.w*b4.w;
    }
    __syncthreads();
  }
  #pragma unroll
  for (int i = 0; i < 4; ++i){
    int row = r0 + ty*4 + i;
    *(float4*)&C[(size_t)row*DMODEL + c0 + tx*4] =
        make_float4(acc[i][0], acc[i][1], acc[i][2], acc[i][3]);
  }
}

// ---------------- attention coefficients es/ed per (row, head) ----------------
__global__ void attn_coef_kernel(const float* __restrict__ H, const float* __restrict__ a_s,
                                 const float* __restrict__ a_d, float* __restrict__ es,
                                 float* __restrict__ ed){
  int row = blockIdx.x; int tid = threadIdx.x;
  float v = H[(size_t)row*DMODEL + tid];
  int h = tid >> 7, dc = tid & 127;
  float ps = v * a_s[h*HID + dc];
  float pd = v * a_d[h*HID + dc];
  #pragma unroll
  for (int o = 32; o > 0; o >>= 1){ ps += __shfl_down(ps, o); pd += __shfl_down(pd, o); }
  __shared__ float rs[4], rd[4];
  int w = tid >> 6, lane = tid & 63;
  if (lane == 0){ rs[w] = ps; rd[w] = pd; }
  __syncthreads();
  if (tid == 0)  { es[row*2+0] = rs[0]+rs[1]; ed[row*2+0] = rd[0]+rd[1]; }
  if (tid == 128){ es[row*2+1] = rs[2]+rs[3]; ed[row*2+1] = rd[2]+rd[3]; }
}

// ---------------- GAT edge-softmax aggregation (one block per (b,dst)) ----------------
__global__ __launch_bounds__(256) void agg_kernel(const float* __restrict__ H,
    const float* __restrict__ es, const float* __restrict__ ed,
    const int* __restrict__ rp, const int* __restrict__ ssrc,
    const float* __restrict__ bias, float* __restrict__ out, int do_relu){
  int idx = blockIdx.x; int d = idx % NN; int b = idx / NN;
  int tid = threadIdx.x;
  const int base = b*NN;
  int e0 = rp[d], e1 = rp[d+1];
  __shared__ float sred[8];
  __shared__ float sbc[4];      // m0, m1, inv0, inv1
  __shared__ int   lsrc[128];
  __shared__ float lalpha[256];

  float edv0 = ed[(size_t)(base+d)*2+0];
  float edv1 = ed[(size_t)(base+d)*2+1];
  float self0 = leaky(es[(size_t)(base+d)*2+0] + edv0);
  float self1 = leaky(es[(size_t)(base+d)*2+1] + edv1);

  // pass 1: per-head max (self-loop included via init)
  float m0 = self0, m1 = self1;
  for (int e = e0 + tid; e < e1; e += 256){
    int s = ssrc[e];
    m0 = fmaxf(m0, leaky(es[(size_t)(base+s)*2+0] + edv0));
    m1 = fmaxf(m1, leaky(es[(size_t)(base+s)*2+1] + edv1));
  }
  #pragma unroll
  for (int o = 32; o > 0; o >>= 1){ m0 = fmaxf(m0, __shfl_down(m0, o)); m1 = fmaxf(m1, __shfl_down(m1, o)); }
  int w = tid >> 6, lane = tid & 63;
  if (lane == 0){ sred[w] = m0; sred[4+w] = m1; }
  __syncthreads();
  if (tid == 0){
    sbc[0] = fmaxf(fmaxf(sred[0], sred[1]), fmaxf(sred[2], sred[3]));
    sbc[1] = fmaxf(fmaxf(sred[4], sred[5]), fmaxf(sred[6], sred[7]));
  }
  __syncthreads();
  m0 = sbc[0]; m1 = sbc[1];

  // pass 2: per-head sum(exp)
  float s0 = (tid == 0) ? expf(self0 - m0) : 0.f;
  float s1 = (tid == 0) ? expf(self1 - m1) : 0.f;
  for (int e = e0 + tid; e < e1; e += 256){
    int s = ssrc[e];
    s0 += expf(leaky(es[(size_t)(base+s)*2+0] + edv0) - m0);
    s1 += expf(leaky(es[(size_t)(base+s)*2+1] + edv1) - m1);
  }
  #pragma unroll
  for (int o = 32; o > 0; o >>= 1){ s0 += __shfl_down(s0, o); s1 += __shfl_down(s1, o); }
  __syncthreads();
  if (lane == 0){ sred[w] = s0; sred[4+w] = s1; }
  __syncthreads();
  if (tid == 0){
    sbc[2] = 1.f/(sred[0]+sred[1]+sred[2]+sred[3]);
    sbc[3] = 1.f/(sred[4]+sred[5]+sred[6]+sred[7]);
  }
  __syncthreads();

  // pass 3: weighted aggregation; thread = output channel
  int h = tid >> 7;
  float mh   = h ? sbc[1] : sbc[0];
  float inv  = h ? sbc[3] : sbc[2];
  float selfh = h ? self1 : self0;
  float acc = expf(selfh - mh) * inv * H[(size_t)(base+d)*DMODEL + tid];
  for (int ch = e0; ch < e1; ch += 128){
    int nc = (e1 - ch < 128) ? (e1 - ch) : 128;
    __syncthreads();
    if (tid < nc) lsrc[tid] = ssrc[ch + tid];
    __syncthreads();
    if (tid < 2*nc){
      int ei = tid >> 1, h2 = tid & 1;
      int s = lsrc[ei];
      float ml  = h2 ? sbc[1] : sbc[0];
      float edl = h2 ? edv1   : edv0;
      float ivl = h2 ? sbc[3] : sbc[2];
      lalpha[h2*128 + ei] = expf(leaky(es[(size_t)(base+s)*2+h2] + edl) - ml) * ivl;
    }
    __syncthreads();
    for (int i = 0; i < nc; ++i){
      int s = lsrc[i];
      acc += lalpha[h*128 + i] * H[(size_t)(base+s)*DMODEL + tid];
    }
  }
  acc += bias[tid];
  if (do_relu) acc = fmaxf(acc, 0.f);
  out[(size_t)(base+d)*DMODEL + tid] = acc;
}

// ---------------- node mean-pool (two-stage deterministic reduce) ----------------
#define PCH 64
__global__ void pool1_kernel(const float* __restrict__ X2, float* __restrict__ part){
  int b = blockIdx.x / PCH; int ch = blockIdx.x % PCH; int c = threadIdx.x;
  const int RPC = (NN + PCH - 1) / PCH;  // 157
  int d0 = ch*RPC, d1 = d0+RPC < NN ? d0+RPC : NN;
  float s = 0.f;
  for (int d = d0; d < d1; ++d) s += X2[(size_t)(b*NN + d)*DMODEL + c];
  part[(size_t)blockIdx.x*DMODEL + c] = s;
}
__global__ void pool2_kernel(const float* __restrict__ part, float* __restrict__ pooled, int t){
  int b = blockIdx.x; int c = threadIdx.x;
  float s = 0.f;
  for (int ch = 0; ch < PCH; ++ch) s += part[(size_t)(b*PCH + ch)*DMODEL + c];
  pooled[(size_t)(t*NB + b)*DMODEL + c] = s * (1.f/NN);
}

// ---------------- GRU over T + mean + classifier (one block per batch) ----------------
__global__ __launch_bounds__(128) void gru_kernel(const float* __restrict__ pooled,
    const float* __restrict__ Wih, const float* __restrict__ Whh,
    const float* __restrict__ bih, const float* __restrict__ bhh,
    const float* __restrict__ Wc, const float* __restrict__ bc, float* __restrict__ outp){
  int b = blockIdx.x; int j = threadIdx.x;
  __shared__ float xs[256], hs[128], fin[128];
  hs[j] = 0.f;
  float macc = 0.f;
  const float* Wr = Wih + (size_t)j*DMODEL;
  const float* Wz = Wih + (size_t)(128+j)*DMODEL;
  const float* Wn = Wih + (size_t)(256+j)*DMODEL;
  const float* Ur = Whh + (size_t)j*HID;
  const float* Uz = Whh + (size_t)(128+j)*HID;
  const float* Un = Whh + (size_t)(256+j)*HID;
  for (int t = 0; t < TT; ++t){
    __syncthreads();
    xs[j]     = pooled[(size_t)(t*NB + b)*DMODEL + j];
    xs[128+j] = pooled[(size_t)(t*NB + b)*DMODEL + 128 + j];
    __syncthreads();
    float gr = bih[j], gz = bih[128+j], gn = bih[256+j];
    #pragma unroll 4
    for (int k = 0; k < DMODEL; ++k){ float x = xs[k]; gr += Wr[k]*x; gz += Wz[k]*x; gn += Wn[k]*x; }
    float hr = bhh[j], hz = bhh[128+j], hn = bhh[256+j];
    #pragma unroll 4
    for (int k = 0; k < HID; ++k){ float hv = hs[k]; hr += Ur[k]*hv; hz += Uz[k]*hv; hn += Un[k]*hv; }
    float rg = 1.f/(1.f + expf(-(gr+hr)));
    float zg = 1.f/(1.f + expf(-(gz+hz)));
    float ng = tanhf(gn + rg*hn);
    float hnew = (1.f - zg)*ng + zg*hs[j];
    __syncthreads();
    hs[j] = hnew;
    macc += hnew;
  }
  fin[j] = macc * (1.f/TT);
  __syncthreads();
  if (j < 10){
    float s = bc[j];
    for (int k = 0; k < HID; ++k) s += fin[k]*Wc[k*10 + j];
    outp[b*10 + j] = s;
  }
}

// ---------------- launch ----------------
extern "C" void kernel_launch(void* const* d_in, const int* in_sizes, int n_in,
                              void* d_out, int out_size, void* d_ws, size_t ws_size,
                              hipStream_t stream){
  const float* x_seq = (const float*)d_in[0];
  const int*   eidx  = (const int*)d_in[1];
  const float* W1    = (const float*)d_in[2];
  const float* a_s1  = (const float*)d_in[3];
  const float* a_d1  = (const float*)d_in[4];
  const float* b1    = (const float*)d_in[5];
  const float* W2    = (const float*)d_in[6];
  const float* a_s2  = (const float*)d_in[7];
  const float* a_d2  = (const float*)d_in[8];
  const float* b2    = (const float*)d_in[9];
  const float* Wih   = (const float*)d_in[10];
  const float* Whh   = (const float*)d_in[11];
  const float* bih   = (const float*)d_in[12];
  const float* bhh   = (const float*)d_in[13];
  const float* Wc    = (const float*)d_in[14];
  const float* bc    = (const float*)d_in[15];
  float* outp = (float*)d_out;

  char* ws = (char*)d_ws;
  size_t off = 0;
  auto alloc = [&](size_t bytes)->char*{
    char* p = ws + off; off += (bytes + 511) & ~(size_t)511; return p;
  };
  int*   counts = (int*)  alloc((size_t)TT*NN*4);
  int*   rp     = (int*)  alloc((size_t)TT*(NN+1)*4);
  int*   cursor = (int*)  alloc((size_t)TT*NN*4);
  int*   ssrc   = (int*)  alloc((size_t)TT*EE*4);
  float* H      = (float*)alloc((size_t)NB*NN*DMODEL*4);
  float* X1     = (float*)alloc((size_t)NB*NN*DMODEL*4);
  float* es     = (float*)alloc((size_t)NB*NN*2*4);
  float* ed     = (float*)alloc((size_t)NB*NN*2*4);
  float* part   = (float*)alloc((size_t)NB*PCH*DMODEL*4);
  float* pooled = (float*)alloc((size_t)TT*NB*DMODEL*4);
  (void)ws_size; (void)in_sizes; (void)n_in; (void)out_size;

  hipMemsetAsync(counts, 0, (size_t)TT*NN*4, stream);
  hist_kernel   <<<(TT*EE)/256, 256, 0, stream>>>(eidx, counts);
  scan_kernel   <<<TT, 256, 0, stream>>>(counts, rp, cursor);
  scatter_kernel<<<(TT*EE)/256, 256, 0, stream>>>(eidx, cursor, ssrc);

  for (int t = 0; t < TT; ++t){
    const int* rpt = rp + t*(NN+1);
    const int* st  = ssrc + (size_t)t*EE;
    // layer 1
    gemm_kernel<FIN><<<dim3((NB*NN)/64, DMODEL/64), 256, 0, stream>>>(
        x_seq + (size_t)t*NN*FIN, (size_t)TT*NN*FIN, W1, H);
    attn_coef_kernel<<<NB*NN, 256, 0, stream>>>(H, a_s1, a_d1, es, ed);
    agg_kernel<<<NB*NN, 256, 0, stream>>>(H, es, ed, rpt, st, b1, X1, 1);
    // layer 2
    gemm_kernel<DMODEL><<<dim3((NB*NN)/64, DMODEL/64), 256, 0, stream>>>(
        X1, (size_t)NN*DMODEL, W2, H);
    attn_coef_kernel<<<NB*NN, 256, 0, stream>>>(H, a_s2, a_d2, es, ed);
    agg_kernel<<<NB*NN, 256, 0, stream>>>(H, es, ed, rpt, st, b2, X1, 0);
    // pool
    pool1_kernel<<<NB*PCH, 256, 0, stream>>>(X1, part);
    pool2_kernel<<<NB, 256, 0, stream>>>(part, pooled, t);
  }
  gru_kernel<<<NB, 128, 0, stream>>>(pooled, Wih, Whh, bih, bhh, Wc, bc, outp);
}

// Round 3
// 4489.021 us; speedup vs baseline: 1.0831x; 1.0831x over previous
//
#include <hip/hip_runtime.h>
#include <cstdint>

#define NB 4       // batch
#define TT 8       // timesteps
#define NN 10000   // nodes
#define FIN 128
#define HID 128
#define EE 320000  // edges per timestep (before self-loops)
#define DMODEL 256 // HEADS*HID
#define NEG 0.2f

__device__ __forceinline__ float leaky(float x){ return x >= 0.f ? x : NEG*x; }

// ---------------- CSR build (counting sort by dst, per t) ----------------
__global__ void hist_kernel(const int* __restrict__ eidx, int* __restrict__ counts){
  int idx = blockIdx.x*256 + threadIdx.x;        // t*EE + e, grid exactly T*E/256
  int t = idx / EE, e = idx - t*EE;
  int dst = eidx[(size_t)t*2*EE + EE + e];
  atomicAdd(&counts[t*NN + dst], 1);
}

__global__ void scan_kernel(const int* __restrict__ counts, int* __restrict__ rp,
                            int* __restrict__ cursor){
  int t = blockIdx.x; int tid = threadIdx.x;
  __shared__ int lds[256];
  const int CH = 40;                              // ceil(10000/256)
  int lo = tid*CH, hi = lo+CH < NN ? lo+CH : NN;
  int s = 0;
  for (int i = lo; i < hi; ++i) s += counts[t*NN + i];
  lds[tid] = s; __syncthreads();
  for (int off = 1; off < 256; off <<= 1){
    int v = (tid >= off) ? lds[tid-off] : 0; __syncthreads();
    lds[tid] += v; __syncthreads();
  }
  int run = (tid == 0) ? 0 : lds[tid-1];
  for (int i = lo; i < hi; ++i){
    rp[t*(NN+1) + i] = run; cursor[t*NN + i] = run; run += counts[t*NN + i];
  }
  if (tid == 255) rp[t*(NN+1) + NN] = lds[255];
}

__global__ void scatter_kernel(const int* __restrict__ eidx, int* __restrict__ cursor,
                               int* __restrict__ ssrc){
  int idx = blockIdx.x*256 + threadIdx.x;
  int t = idx / EE, e = idx - t*EE;
  int src = eidx[(size_t)t*2*EE + e];
  int dst = eidx[(size_t)t*2*EE + EE + e];
  int pos = atomicAdd(&cursor[t*NN + dst], 1);
  ssrc[(size_t)t*EE + pos] = src;
}

// ------- fp32 GEMM 128x128 tile, 8x8 microtile, fused es/ed epilogue -------
// C[M][256] = A @ W[K][256];  es/ed[r][head] = dot(C_row_head, a_s/a_d).
// Column block (BN=128) == one head, so es/ed need no cross-block reduce.
// Row r of A lives at A + (r/NN)*bstride + (r%NN)*K.
template<int K>
__global__ __launch_bounds__(256) void gemm_attn_kernel(const float* __restrict__ A, size_t bstride,
    const float* __restrict__ W, const float* __restrict__ av_s, const float* __restrict__ av_d,
    float* __restrict__ C, float* __restrict__ es, float* __restrict__ ed, int M){
  __shared__ float As[16][132];   // transposed A tile (k, row), padded
  __shared__ float Bs[16][128];   // (k, col)
  int tid = threadIdx.x;
  int r0 = blockIdx.x*128, c0 = blockIdx.y*128;
  int ty = tid >> 4, tx = tid & 15;

  // A loader: 128 rows x 4 float4 = 512 f4; this thread does idx and idx+256
  const float* arow0; const float* arow1;
  {
    int r_ = r0 + (tid >> 2); if (r_ >= M) r_ = M-1;
    int b = r_/NN, n = r_ - b*NN;
    arow0 = A + (size_t)b*bstride + (size_t)n*K + (tid & 3)*4;
    r_ = r0 + 64 + (tid >> 2); if (r_ >= M) r_ = M-1;
    b = r_/NN; n = r_ - b*NN;
    arow1 = A + (size_t)b*bstride + (size_t)n*K + (tid & 3)*4;
  }
  // B loader: 16 k-rows x 32 f4
  const float* brow0 = W + (size_t)(tid>>5)*DMODEL + c0 + (tid & 31)*4;
  const float* brow1 = W + (size_t)((tid>>5)+8)*DMODEL + c0 + (tid & 31)*4;

  float acc[8][8];
  #pragma unroll
  for (int i = 0; i < 8; ++i)
    #pragma unroll
    for (int j = 0; j < 8; ++j) acc[i][j] = 0.f;

  int r_loc = tid >> 2, cq = (tid & 3)*4;
  for (int k0 = 0; k0 < K; k0 += 16){
    float4 a0 = *(const float4*)(arow0 + k0);
    float4 a1 = *(const float4*)(arow1 + k0);
    float4 b0 = *(const float4*)(brow0 + (size_t)k0*DMODEL);
    float4 b1 = *(const float4*)(brow1 + (size_t)k0*DMODEL);
    __syncthreads();               // previous iteration done reading LDS
    As[cq+0][r_loc] = a0.x; As[cq+1][r_loc] = a0.y; As[cq+2][r_loc] = a0.z; As[cq+3][r_loc] = a0.w;
    As[cq+0][64+r_loc] = a1.x; As[cq+1][64+r_loc] = a1.y; As[cq+2][64+r_loc] = a1.z; As[cq+3][64+r_loc] = a1.w;
    *(float4*)&Bs[tid>>5][(tid&31)*4]     = b0;
    *(float4*)&Bs[(tid>>5)+8][(tid&31)*4] = b1;
    __syncthreads();
    #pragma unroll
    for (int kk = 0; kk < 16; ++kk){
      float4 aA = *(const float4*)&As[kk][ty*4];
      float4 aB = *(const float4*)&As[kk][64+ty*4];
      float4 bA = *(const float4*)&Bs[kk][tx*4];
      float4 bB = *(const float4*)&Bs[kk][64+tx*4];
      float ar[8] = {aA.x,aA.y,aA.z,aA.w,aB.x,aB.y,aB.z,aB.w};
      float br[8] = {bA.x,bA.y,bA.z,bA.w,bB.x,bB.y,bB.z,bB.w};
      #pragma unroll
      for (int i = 0; i < 8; ++i)
        #pragma unroll
        for (int j = 0; j < 8; ++j) acc[i][j] += ar[i]*br[j];
    }
  }

  // attention-vector values for this thread's 8 columns (head == c0>>7)
  float as_c[8], ad_c[8];
  #pragma unroll
  for (int j = 0; j < 8; ++j){
    int c = c0 + (j < 4 ? tx*4+j : 64+tx*4+(j-4));
    as_c[j] = av_s[c]; ad_c[j] = av_d[c];
  }
  int hsel = c0 >> 7;
  #pragma unroll
  for (int ii = 0; ii < 8; ++ii){
    int r = r0 + (ii < 4 ? ty*4+ii : 64+ty*4+(ii-4));
    // es/ed partial + 16-lane tree reduce (tx groups are lane-contiguous)
    float ls = 0.f, ld_ = 0.f;
    #pragma unroll
    for (int j = 0; j < 8; ++j){ ls += acc[ii][j]*as_c[j]; ld_ += acc[ii][j]*ad_c[j]; }
    #pragma unroll
    for (int o = 8; o > 0; o >>= 1){ ls += __shfl_down(ls, o); ld_ += __shfl_down(ld_, o); }
    if (r < M){
      if (tx == 0){ es[(size_t)r*2 + hsel] = ls; ed[(size_t)r*2 + hsel] = ld_; }
      *(float4*)&C[(size_t)r*DMODEL + c0 + tx*4]      = make_float4(acc[ii][0],acc[ii][1],acc[ii][2],acc[ii][3]);
      *(float4*)&C[(size_t)r*DMODEL + c0 + 64 + tx*4] = make_float4(acc[ii][4],acc[ii][5],acc[ii][6],acc[ii][7]);
    }
  }
}

// ---------------- GAT edge-softmax aggregation (one block per (b,dst)) ----------------
__global__ __launch_bounds__(256) void agg_kernel(const float* __restrict__ H,
    const float* __restrict__ es, const float* __restrict__ ed,
    const int* __restrict__ rp, const int* __restrict__ ssrc,
    const float* __restrict__ bias, float* __restrict__ out, int do_relu){
  int idx = blockIdx.x; int d = idx % NN; int b = idx / NN;
  int tid = threadIdx.x;
  const int base = b*NN;
  int e0 = rp[d], e1 = rp[d+1];
  __shared__ float sred[8];
  __shared__ float sbc[4];      // m0, m1, inv0, inv1
  __shared__ int   lsrc[128];
  __shared__ float lalpha[256];

  float edv0 = ed[(size_t)(base+d)*2+0];
  float edv1 = ed[(size_t)(base+d)*2+1];
  float self0 = leaky(es[(size_t)(base+d)*2+0] + edv0);
  float self1 = leaky(es[(size_t)(base+d)*2+1] + edv1);

  // pass 1: per-head max (self-loop included via init)
  float m0 = self0, m1 = self1;
  for (int e = e0 + tid; e < e1; e += 256){
    int s = ssrc[e];
    m0 = fmaxf(m0, leaky(es[(size_t)(base+s)*2+0] + edv0));
    m1 = fmaxf(m1, leaky(es[(size_t)(base+s)*2+1] + edv1));
  }
  #pragma unroll
  for (int o = 32; o > 0; o >>= 1){ m0 = fmaxf(m0, __shfl_down(m0, o)); m1 = fmaxf(m1, __shfl_down(m1, o)); }
  int w = tid >> 6, lane = tid & 63;
  if (lane == 0){ sred[w] = m0; sred[4+w] = m1; }
  __syncthreads();
  if (tid == 0){
    sbc[0] = fmaxf(fmaxf(sred[0], sred[1]), fmaxf(sred[2], sred[3]));
    sbc[1] = fmaxf(fmaxf(sred[4], sred[5]), fmaxf(sred[6], sred[7]));
  }
  __syncthreads();
  m0 = sbc[0]; m1 = sbc[1];

  // pass 2: per-head sum(exp)
  float s0 = (tid == 0) ? expf(self0 - m0) : 0.f;
  float s1 = (tid == 0) ? expf(self1 - m1) : 0.f;
  for (int e = e0 + tid; e < e1; e += 256){
    int s = ssrc[e];
    s0 += expf(leaky(es[(size_t)(base+s)*2+0] + edv0) - m0);
    s1 += expf(leaky(es[(size_t)(base+s)*2+1] + edv1) - m1);
  }
  #pragma unroll
  for (int o = 32; o > 0; o >>= 1){ s0 += __shfl_down(s0, o); s1 += __shfl_down(s1, o); }
  __syncthreads();
  if (lane == 0){ sred[w] = s0; sred[4+w] = s1; }
  __syncthreads();
  if (tid == 0){
    sbc[2] = 1.f/(sred[0]+sred[1]+sred[2]+sred[3]);
    sbc[3] = 1.f/(sred[4]+sred[5]+sred[6]+sred[7]);
  }
  __syncthreads();

  // pass 3: weighted aggregation; thread = output channel
  int h = tid >> 7;
  float mh    = h ? sbc[1] : sbc[0];
  float inv   = h ? sbc[3] : sbc[2];
  float selfh = h ? self1 : self0;
  float acc = expf(selfh - mh) * inv * H[(size_t)(base+d)*DMODEL + tid];
  for (int ch = e0; ch < e1; ch += 128){
    int nc = (e1 - ch < 128) ? (e1 - ch) : 128;
    __syncthreads();
    if (tid < nc) lsrc[tid] = ssrc[ch + tid];
    __syncthreads();
    if (tid < 2*nc){
      int ei = tid >> 1, h2 = tid & 1;
      int s = lsrc[ei];
      float ml  = h2 ? sbc[1] : sbc[0];
      float edl = h2 ? edv1   : edv0;
      float ivl = h2 ? sbc[3] : sbc[2];
      lalpha[h2*128 + ei] = expf(leaky(es[(size_t)(base+s)*2+h2] + edl) - ml) * ivl;
    }
    __syncthreads();
    // 4-way unrolled independent accumulators (break dependent FMA chain)
    int i = 0;
    float a0 = 0.f, a1 = 0.f, a2 = 0.f, a3 = 0.f;
    for (; i + 4 <= nc; i += 4){
      a0 += lalpha[h*128+i+0] * H[(size_t)(base+lsrc[i+0])*DMODEL + tid];
      a1 += lalpha[h*128+i+1] * H[(size_t)(base+lsrc[i+1])*DMODEL + tid];
      a2 += lalpha[h*128+i+2] * H[(size_t)(base+lsrc[i+2])*DMODEL + tid];
      a3 += lalpha[h*128+i+3] * H[(size_t)(base+lsrc[i+3])*DMODEL + tid];
    }
    for (; i < nc; ++i) a0 += lalpha[h*128+i] * H[(size_t)(base+lsrc[i])*DMODEL + tid];
    acc += (a0 + a1) + (a2 + a3);
  }
  acc += bias[tid];
  if (do_relu) acc = fmaxf(acc, 0.f);
  out[(size_t)(base+d)*DMODEL + tid] = acc;
}

// ---------------- node mean-pool (two-stage deterministic reduce) ----------------
#define PCH 64
__global__ void pool1_kernel(const float* __restrict__ X2, float* __restrict__ part){
  int b = blockIdx.x / PCH; int ch = blockIdx.x % PCH; int c = threadIdx.x;
  const int RPC = (NN + PCH - 1) / PCH;  // 157
  int d0 = ch*RPC, d1 = d0+RPC < NN ? d0+RPC : NN;
  float s = 0.f;
  for (int d = d0; d < d1; ++d) s += X2[(size_t)(b*NN + d)*DMODEL + c];
  part[(size_t)blockIdx.x*DMODEL + c] = s;
}
__global__ void pool2_kernel(const float* __restrict__ part, float* __restrict__ pooled, int t){
  int b = blockIdx.x; int c = threadIdx.x;
  float s = 0.f;
  for (int ch = 0; ch < PCH; ++ch) s += part[(size_t)(b*PCH + ch)*DMODEL + c];
  pooled[(size_t)(t*NB + b)*DMODEL + c] = s * (1.f/NN);
}

// ---------------- GRU: parallel gi precompute + LDS-resident recurrence ----------------
// gi[row=t*NB+b][384] = pooled[row] @ Wih.T + bih  (all 32 rows in parallel)
__global__ __launch_bounds__(384) void gi_kernel(const float* __restrict__ pooled,
    const float* __restrict__ Wih, const float* __restrict__ bih, float* __restrict__ gi){
  int row = blockIdx.x; int j = threadIdx.x;
  __shared__ float xs[256];
  if (j < 256) xs[j] = pooled[(size_t)row*DMODEL + j];
  __syncthreads();
  const float4* Wr = (const float4*)(Wih + (size_t)j*DMODEL);
  float s = bih[j];
  #pragma unroll 8
  for (int k = 0; k < 64; ++k){
    float4 wv = Wr[k];
    s += wv.x*xs[k*4] + wv.y*xs[k*4+1] + wv.z*xs[k*4+2] + wv.w*xs[k*4+3];
  }
  gi[(size_t)row*384 + j] = s;
}

// recurrence: block per b; thread j<384 computes gh_j from LDS h (128 MACs);
// threads 0..127 apply gates; classifier fused at the end.
__global__ __launch_bounds__(384) void rec_kernel(const float* __restrict__ gi,
    const float* __restrict__ Whh, const float* __restrict__ bhh,
    const float* __restrict__ Wc, const float* __restrict__ bc, float* __restrict__ outp){
  int b = blockIdx.x; int j = threadIdx.x;
  __shared__ float hs[128], ghs[384], fin[128];
  if (j < 128) hs[j] = 0.f;
  float macc = 0.f;
  const float4* Ur = (const float4*)(Whh + (size_t)j*HID);
  float bh = bhh[j];
  for (int t = 0; t < TT; ++t){
    __syncthreads();                       // hs ready
    float s = bh;
    #pragma unroll 8
    for (int k = 0; k < 32; ++k){
      float4 wv = Ur[k];
      s += wv.x*hs[k*4] + wv.y*hs[k*4+1] + wv.z*hs[k*4+2] + wv.w*hs[k*4+3];
    }
    ghs[j] = s; __syncthreads();
    float hnew = 0.f;
    if (j < 128){
      const float* g = gi + (size_t)(t*NB + b)*384;
      float r = 1.f/(1.f + expf(-(g[j] + ghs[j])));
      float z = 1.f/(1.f + expf(-(g[128+j] + ghs[128+j])));
      float n = tanhf(g[256+j] + r*ghs[256+j]);
      hnew = (1.f - z)*n + z*hs[j];
    }
    __syncthreads();
    if (j < 128){ hs[j] = hnew; macc += hnew; }
  }
  if (j < 128) fin[j] = macc * (1.f/TT);
  __syncthreads();
  if (j < 10){
    float s = bc[j];
    for (int k = 0; k < 128; ++k) s += fin[k]*Wc[k*10 + j];
    outp[b*10 + j] = s;
  }
}

// ---------------- launch ----------------
extern "C" void kernel_launch(void* const* d_in, const int* in_sizes, int n_in,
                              void* d_out, int out_size, void* d_ws, size_t ws_size,
                              hipStream_t stream){
  const float* x_seq = (const float*)d_in[0];
  const int*   eidx  = (const int*)d_in[1];
  const float* W1    = (const float*)d_in[2];
  const float* a_s1  = (const float*)d_in[3];
  const float* a_d1  = (const float*)d_in[4];
  const float* b1    = (const float*)d_in[5];
  const float* W2    = (const float*)d_in[6];
  const float* a_s2  = (const float*)d_in[7];
  const float* a_d2  = (const float*)d_in[8];
  const float* b2    = (const float*)d_in[9];
  const float* Wih   = (const float*)d_in[10];
  const float* Whh   = (const float*)d_in[11];
  const float* bih   = (const float*)d_in[12];
  const float* bhh   = (const float*)d_in[13];
  const float* Wc    = (const float*)d_in[14];
  const float* bc    = (const float*)d_in[15];
  float* outp = (float*)d_out;

  char* ws = (char*)d_ws;
  size_t off = 0;
  auto alloc = [&](size_t bytes)->char*{
    char* p = ws + off; off += (bytes + 511) & ~(size_t)511; return p;
  };
  int*   counts = (int*)  alloc((size_t)TT*NN*4);
  int*   rp     = (int*)  alloc((size_t)TT*(NN+1)*4);
  int*   cursor = (int*)  alloc((size_t)TT*NN*4);
  int*   ssrc   = (int*)  alloc((size_t)TT*EE*4);
  float* H      = (float*)alloc((size_t)NB*NN*DMODEL*4);
  float* X1     = (float*)alloc((size_t)NB*NN*DMODEL*4);
  float* es     = (float*)alloc((size_t)NB*NN*2*4);
  float* ed     = (float*)alloc((size_t)NB*NN*2*4);
  float* part   = (float*)alloc((size_t)NB*PCH*DMODEL*4);
  float* pooled = (float*)alloc((size_t)TT*NB*DMODEL*4);
  float* gib    = (float*)alloc((size_t)TT*NB*384*4);
  (void)ws_size; (void)in_sizes; (void)n_in; (void)out_size;

  const int M = NB*NN;                      // 40000
  const int GX = (M + 127)/128;             // 313

  hipMemsetAsync(counts, 0, (size_t)TT*NN*4, stream);
  hist_kernel   <<<(TT*EE)/256, 256, 0, stream>>>(eidx, counts);
  scan_kernel   <<<TT, 256, 0, stream>>>(counts, rp, cursor);
  scatter_kernel<<<(TT*EE)/256, 256, 0, stream>>>(eidx, cursor, ssrc);

  for (int t = 0; t < TT; ++t){
    const int* rpt = rp + t*(NN+1);
    const int* st  = ssrc + (size_t)t*EE;
    // layer 1 (GEMM + fused es/ed)
    gemm_attn_kernel<FIN><<<dim3(GX, 2), 256, 0, stream>>>(
        x_seq + (size_t)t*NN*FIN, (size_t)TT*NN*FIN, W1, a_s1, a_d1, H, es, ed, M);
    agg_kernel<<<M, 256, 0, stream>>>(H, es, ed, rpt, st, b1, X1, 1);
    // layer 2
    gemm_attn_kernel<DMODEL><<<dim3(GX, 2), 256, 0, stream>>>(
        X1, (size_t)NN*DMODEL, W2, a_s2, a_d2, H, es, ed, M);
    agg_kernel<<<M, 256, 0, stream>>>(H, es, ed, rpt, st, b2, X1, 0);
    // pool
    pool1_kernel<<<NB*PCH, 256, 0, stream>>>(X1, part);
    pool2_kernel<<<NB, 256, 0, stream>>>(part, pooled, t);
  }
  gi_kernel <<<TT*NB, 384, 0, stream>>>(pooled, Wih, bih, gib);
  rec_kernel<<<NB, 384, 0, stream>>>(gib, Whh, bhh, Wc, bc, outp);
}

// Round 4
// 4212.957 us; speedup vs baseline: 1.1541x; 1.0655x over previous
//
#include <hip/hip_runtime.h>
#include <cstdint>

#define NB 4       // batch
#define TT 8       // timesteps
#define NN 10000   // nodes
#define FIN 128
#define HID 128
#define EE 320000  // edges per timestep (before self-loops)
#define DMODEL 256 // HEADS*HID
#define MTOT (NB*NN)
#define NEG 0.2f

__device__ __forceinline__ float leaky(float x){ return x >= 0.f ? x : NEG*x; }

// ---------------- CSR build (counting sort by dst, per t) ----------------
__global__ void hist_kernel(const int* __restrict__ eidx, int* __restrict__ counts){
  int idx = blockIdx.x*256 + threadIdx.x;        // t*EE + e, grid exactly T*E/256
  int t = idx / EE, e = idx - t*EE;
  int dst = eidx[(size_t)t*2*EE + EE + e];
  atomicAdd(&counts[t*NN + dst], 1);
}

__global__ void scan_kernel(const int* __restrict__ counts, int* __restrict__ rp,
                            int* __restrict__ cursor){
  int t = blockIdx.x; int tid = threadIdx.x;
  __shared__ int lds[256];
  const int CH = 40;                              // ceil(10000/256)
  int lo = tid*CH, hi = lo+CH < NN ? lo+CH : NN;
  int s = 0;
  for (int i = lo; i < hi; ++i) s += counts[t*NN + i];
  lds[tid] = s; __syncthreads();
  for (int off = 1; off < 256; off <<= 1){
    int v = (tid >= off) ? lds[tid-off] : 0; __syncthreads();
    lds[tid] += v; __syncthreads();
  }
  int run = (tid == 0) ? 0 : lds[tid-1];
  for (int i = lo; i < hi; ++i){
    rp[t*(NN+1) + i] = run; cursor[t*NN + i] = run; run += counts[t*NN + i];
  }
  if (tid == 255) rp[t*(NN+1) + NN] = lds[255];
}

__global__ void scatter_kernel(const int* __restrict__ eidx, int* __restrict__ cursor,
                               int* __restrict__ ssrc){
  int idx = blockIdx.x*256 + threadIdx.x;
  int t = idx / EE, e = idx - t*EE;
  int src = eidx[(size_t)t*2*EE + e];
  int dst = eidx[(size_t)t*2*EE + EE + e];
  int pos = atomicAdd(&cursor[t*NN + dst], 1);
  ssrc[(size_t)t*EE + pos] = src;
}

// ------- fp32 GEMM 128x128 tile, 8x8 microtile, fused es/ed epilogue -------
// Output in HEAD-SPLIT layout: C[head][r][128] (r = b*NN+n), es/ed[head][r].
// A input: K==128 -> rows at A0 + b*bstride + n*128;
//          K==256 -> split halves: A0[r][128] (k<128), A1[r][128] (k>=128).
template<int K>
__global__ __launch_bounds__(256) void gemm_attn_kernel(const float* __restrict__ A0,
    const float* __restrict__ A1, size_t bstride,
    const float* __restrict__ W, const float* __restrict__ av_s, const float* __restrict__ av_d,
    float* __restrict__ C, float* __restrict__ es, float* __restrict__ ed, int M){
  __shared__ float As[16][132];   // transposed A tile (k, row), padded
  __shared__ float Bs[16][128];   // (k, col)
  int tid = threadIdx.x;
  int r0 = blockIdx.x*128, c0 = blockIdx.y*128;
  int ty = tid >> 4, tx = tid & 15;

  // A loader: 128 rows; this thread loads rows (tid>>2) and (tid>>2)+64, f4 slot tid&3
  int cq = (tid & 3)*4;
  const float* a0r0; const float* a0r1; const float* a1r0 = nullptr; const float* a1r1 = nullptr;
  {
    int r_ = r0 + (tid >> 2); if (r_ >= M) r_ = M-1;
    int b = r_/NN, n = r_ - b*NN;
    a0r0 = A0 + (size_t)b*bstride + (size_t)n*128 + cq;
    if (K > 128) a1r0 = A1 + (size_t)r_*128 + cq;
    r_ = r0 + 64 + (tid >> 2); if (r_ >= M) r_ = M-1;
    b = r_/NN; n = r_ - b*NN;
    a0r1 = A0 + (size_t)b*bstride + (size_t)n*128 + cq;
    if (K > 128) a1r1 = A1 + (size_t)r_*128 + cq;
  }
  // B loader: 16 k-rows x 32 f4 (absolute k indexing, W contiguous [K][256])
  const float* brow0 = W + (size_t)(tid>>5)*DMODEL + c0 + (tid & 31)*4;
  const float* brow1 = W + (size_t)((tid>>5)+8)*DMODEL + c0 + (tid & 31)*4;

  float acc[8][8];
  #pragma unroll
  for (int i = 0; i < 8; ++i)
    #pragma unroll
    for (int j = 0; j < 8; ++j) acc[i][j] = 0.f;

  int r_loc = tid >> 2;
  #pragma unroll 1
  for (int half = 0; half < K/128; ++half){
    const float* pr0 = half ? a1r0 : a0r0;
    const float* pr1 = half ? a1r1 : a0r1;
    #pragma unroll 1
    for (int k0 = 0; k0 < 128; k0 += 16){
      int kab = half*128 + k0;
      float4 a0v = *(const float4*)(pr0 + k0);
      float4 a1v = *(const float4*)(pr1 + k0);
      float4 b0v = *(const float4*)(brow0 + (size_t)kab*DMODEL);
      float4 b1v = *(const float4*)(brow1 + (size_t)kab*DMODEL);
      __syncthreads();               // previous iteration done reading LDS
      As[cq+0][r_loc] = a0v.x; As[cq+1][r_loc] = a0v.y; As[cq+2][r_loc] = a0v.z; As[cq+3][r_loc] = a0v.w;
      As[cq+0][64+r_loc] = a1v.x; As[cq+1][64+r_loc] = a1v.y; As[cq+2][64+r_loc] = a1v.z; As[cq+3][64+r_loc] = a1v.w;
      *(float4*)&Bs[tid>>5][(tid&31)*4]     = b0v;
      *(float4*)&Bs[(tid>>5)+8][(tid&31)*4] = b1v;
      __syncthreads();
      #pragma unroll
      for (int kk = 0; kk < 16; ++kk){
        float4 aA = *(const float4*)&As[kk][ty*4];
        float4 aB = *(const float4*)&As[kk][64+ty*4];
        float4 bA = *(const float4*)&Bs[kk][tx*4];
        float4 bB = *(const float4*)&Bs[kk][64+tx*4];
        float ar[8] = {aA.x,aA.y,aA.z,aA.w,aB.x,aB.y,aB.z,aB.w};
        float br[8] = {bA.x,bA.y,bA.z,bA.w,bB.x,bB.y,bB.z,bB.w};
        #pragma unroll
        for (int i = 0; i < 8; ++i)
          #pragma unroll
          for (int j = 0; j < 8; ++j) acc[i][j] += ar[i]*br[j];
      }
    }
  }

  // attention-vector values for this thread's 8 columns (head == c0>>7)
  float as_c[8], ad_c[8];
  #pragma unroll
  for (int j = 0; j < 8; ++j){
    int c = c0 + (j < 4 ? tx*4+j : 64+tx*4+(j-4));
    as_c[j] = av_s[c]; ad_c[j] = av_d[c];
  }
  int hsel = c0 >> 7;
  float* Ch = C + (size_t)hsel*M*128;
  #pragma unroll
  for (int ii = 0; ii < 8; ++ii){
    int r = r0 + (ii < 4 ? ty*4+ii : 64+ty*4+(ii-4));
    float ls = 0.f, ld_ = 0.f;
    #pragma unroll
    for (int j = 0; j < 8; ++j){ ls += acc[ii][j]*as_c[j]; ld_ += acc[ii][j]*ad_c[j]; }
    #pragma unroll
    for (int o = 8; o > 0; o >>= 1){ ls += __shfl_down(ls, o); ld_ += __shfl_down(ld_, o); }
    if (r < M){
      if (tx == 0){ es[(size_t)hsel*M + r] = ls; ed[(size_t)hsel*M + r] = ld_; }
      *(float4*)&Ch[(size_t)r*128 + tx*4]      = make_float4(acc[ii][0],acc[ii][1],acc[ii][2],acc[ii][3]);
      *(float4*)&Ch[(size_t)r*128 + 64 + tx*4] = make_float4(acc[ii][4],acc[ii][5],acc[ii][6],acc[ii][7]);
    }
  }
}

// ------- GAT edge-softmax aggregation, (b,head)-phased: block = (dst, phase) -------
// H/out layout [head][b*NN+n][128]; es/ed layout [head][b*NN+n].
__global__ __launch_bounds__(128) void agg_kernel(const float* __restrict__ H,
    const float* __restrict__ es, const float* __restrict__ ed,
    const int* __restrict__ rp, const int* __restrict__ ssrc,
    const float* __restrict__ bias, float* __restrict__ out, int do_relu){
  int d = blockIdx.x; int ph = blockIdx.y;
  int h = ph & 1, b = ph >> 1;
  int tid = threadIdx.x;
  const size_t reg = (size_t)h*MTOT + (size_t)b*NN;   // row offset of this (h,b) region
  const float* esh = es + reg;
  const float* edh = ed + reg;
  const float* Hh  = H + reg*128;
  int e0 = rp[d], e1 = rp[d+1];
  __shared__ float sred[2];
  __shared__ float sbc2[2];        // m, inv
  __shared__ unsigned int offs[128];
  __shared__ float lal[128];

  float edv  = edh[d];
  float self = leaky(esh[d] + edv);

  // pass 1: max (self-loop included via init)
  float m = self;
  for (int e = e0 + tid; e < e1; e += 128) m = fmaxf(m, leaky(esh[ssrc[e]] + edv));
  #pragma unroll
  for (int o = 32; o > 0; o >>= 1) m = fmaxf(m, __shfl_down(m, o));
  int w = tid >> 6, lane = tid & 63;
  if (lane == 0) sred[w] = m;
  __syncthreads();
  if (tid == 0) sbc2[0] = fmaxf(sred[0], sred[1]);
  __syncthreads();
  m = sbc2[0];

  // pass 2: sum(exp)
  float s0 = (tid == 0) ? expf(self - m) : 0.f;
  for (int e = e0 + tid; e < e1; e += 128) s0 += expf(leaky(esh[ssrc[e]] + edv) - m);
  #pragma unroll
  for (int o = 32; o > 0; o >>= 1) s0 += __shfl_down(s0, o);
  if (lane == 0) sred[w] = s0;
  __syncthreads();
  if (tid == 0) sbc2[1] = 1.f/(sred[0] + sred[1]);
  __syncthreads();
  float inv = sbc2[1];

  // pass 3: weighted aggregation; thread = channel (128 per head)
  float acc = expf(self - m) * inv * Hh[(size_t)d*128 + tid];
  const char* Hb = (const char*)Hh + (size_t)tid*4;
  for (int ch = e0; ch < e1; ch += 128){
    int nc = (e1 - ch < 128) ? (e1 - ch) : 128;
    __syncthreads();
    if (tid < nc){
      int s = ssrc[ch + tid];
      offs[tid] = (unsigned int)(s*512);                 // byte offset of row s
      lal[tid]  = expf(leaky(esh[s] + edv) - m) * inv;
    }
    __syncthreads();
    int i = 0;
    float a0 = 0.f, a1 = 0.f, a2 = 0.f, a3 = 0.f;
    for (; i + 4 <= nc; i += 4){
      a0 += lal[i+0] * *(const float*)(Hb + offs[i+0]);
      a1 += lal[i+1] * *(const float*)(Hb + offs[i+1]);
      a2 += lal[i+2] * *(const float*)(Hb + offs[i+2]);
      a3 += lal[i+3] * *(const float*)(Hb + offs[i+3]);
    }
    for (; i < nc; ++i) a0 += lal[i] * *(const float*)(Hb + offs[i]);
    acc += (a0 + a1) + (a2 + a3);
  }
  acc += bias[h*128 + tid];
  if (do_relu) acc = fmaxf(acc, 0.f);
  out[(reg + d)*128 + tid] = acc;
}

// ---------------- node mean-pool (reads head-split layout) ----------------
#define PCH 64
__global__ void pool1_kernel(const float* __restrict__ X2, float* __restrict__ part){
  int b = blockIdx.x / PCH; int ch = blockIdx.x % PCH; int c = threadIdx.x;
  const int RPC = (NN + PCH - 1) / PCH;  // 157
  int d0 = ch*RPC, d1 = d0+RPC < NN ? d0+RPC : NN;
  int hreg = c >> 7, cw = c & 127;
  const float* Xr = X2 + ((size_t)hreg*MTOT + (size_t)b*NN)*128 + cw;
  float s = 0.f;
  for (int d = d0; d < d1; ++d) s += Xr[(size_t)d*128];
  part[(size_t)blockIdx.x*DMODEL + c] = s;
}
__global__ void pool2_kernel(const float* __restrict__ part, float* __restrict__ pooled, int t){
  int b = blockIdx.x; int c = threadIdx.x;
  float s = 0.f;
  for (int ch = 0; ch < PCH; ++ch) s += part[(size_t)(b*PCH + ch)*DMODEL + c];
  pooled[(size_t)(t*NB + b)*DMODEL + c] = s * (1.f/NN);
}

// ---------------- GRU: parallel gi precompute + LDS-resident recurrence ----------------
// pooled rows are [head0(128) | head1(128)] = same channel order as reference's
// (n,HEADS*dh) reshape?  NOTE: pooled[c] with c<128 = head0 ch c, c>=128 = head1 —
// identical to reference concat order. gi[row=t*NB+b][384] = pooled @ Wih.T + bih.
__global__ __launch_bounds__(384) void gi_kernel(const float* __restrict__ pooled,
    const float* __restrict__ Wih, const float* __restrict__ bih, float* __restrict__ gi){
  int row = blockIdx.x; int j = threadIdx.x;
  __shared__ float xs[256];
  if (j < 256) xs[j] = pooled[(size_t)row*DMODEL + j];
  __syncthreads();
  const float4* Wr = (const float4*)(Wih + (size_t)j*DMODEL);
  float s = bih[j];
  #pragma unroll 8
  for (int k = 0; k < 64; ++k){
    float4 wv = Wr[k];
    s += wv.x*xs[k*4] + wv.y*xs[k*4+1] + wv.z*xs[k*4+2] + wv.w*xs[k*4+3];
  }
  gi[(size_t)row*384 + j] = s;
}

__global__ __launch_bounds__(384) void rec_kernel(const float* __restrict__ gi,
    const float* __restrict__ Whh, const float* __restrict__ bhh,
    const float* __restrict__ Wc, const float* __restrict__ bc, float* __restrict__ outp){
  int b = blockIdx.x; int j = threadIdx.x;
  __shared__ float hs[128], ghs[384], fin[128];
  if (j < 128) hs[j] = 0.f;
  float macc = 0.f;
  const float4* Ur = (const float4*)(Whh + (size_t)j*HID);
  float bh = bhh[j];
  for (int t = 0; t < TT; ++t){
    __syncthreads();                       // hs ready
    float s = bh;
    #pragma unroll 8
    for (int k = 0; k < 32; ++k){
      float4 wv = Ur[k];
      s += wv.x*hs[k*4] + wv.y*hs[k*4+1] + wv.z*hs[k*4+2] + wv.w*hs[k*4+3];
    }
    ghs[j] = s; __syncthreads();
    float hnew = 0.f;
    if (j < 128){
      const float* g = gi + (size_t)(t*NB + b)*384;
      float r = 1.f/(1.f + expf(-(g[j] + ghs[j])));
      float z = 1.f/(1.f + expf(-(g[128+j] + ghs[128+j])));
      float n = tanhf(g[256+j] + r*ghs[256+j]);
      hnew = (1.f - z)*n + z*hs[j];
    }
    __syncthreads();
    if (j < 128){ hs[j] = hnew; macc += hnew; }
  }
  if (j < 128) fin[j] = macc * (1.f/TT);
  __syncthreads();
  if (j < 10){
    float s = bc[j];
    for (int k = 0; k < 128; ++k) s += fin[k]*Wc[k*10 + j];
    outp[b*10 + j] = s;
  }
}

// ---------------- launch ----------------
extern "C" void kernel_launch(void* const* d_in, const int* in_sizes, int n_in,
                              void* d_out, int out_size, void* d_ws, size_t ws_size,
                              hipStream_t stream){
  const float* x_seq = (const float*)d_in[0];
  const int*   eidx  = (const int*)d_in[1];
  const float* W1    = (const float*)d_in[2];
  const float* a_s1  = (const float*)d_in[3];
  const float* a_d1  = (const float*)d_in[4];
  const float* b1    = (const float*)d_in[5];
  const float* W2    = (const float*)d_in[6];
  const float* a_s2  = (const float*)d_in[7];
  const float* a_d2  = (const float*)d_in[8];
  const float* b2    = (const float*)d_in[9];
  const float* Wih   = (const float*)d_in[10];
  const float* Whh   = (const float*)d_in[11];
  const float* bih   = (const float*)d_in[12];
  const float* bhh   = (const float*)d_in[13];
  const float* Wc    = (const float*)d_in[14];
  const float* bc    = (const float*)d_in[15];
  float* outp = (float*)d_out;

  char* ws = (char*)d_ws;
  size_t off = 0;
  auto alloc = [&](size_t bytes)->char*{
    char* p = ws + off; off += (bytes + 511) & ~(size_t)511; return p;
  };
  int*   counts = (int*)  alloc((size_t)TT*NN*4);
  int*   rp     = (int*)  alloc((size_t)TT*(NN+1)*4);
  int*   cursor = (int*)  alloc((size_t)TT*NN*4);
  int*   ssrc   = (int*)  alloc((size_t)TT*EE*4);
  float* H      = (float*)alloc((size_t)MTOT*DMODEL*4);   // [head][M][128]
  float* X1     = (float*)alloc((size_t)MTOT*DMODEL*4);   // [head][M][128]
  float* es     = (float*)alloc((size_t)2*MTOT*4);        // [head][M]
  float* ed     = (float*)alloc((size_t)2*MTOT*4);
  float* part   = (float*)alloc((size_t)NB*PCH*DMODEL*4);
  float* pooled = (float*)alloc((size_t)TT*NB*DMODEL*4);
  float* gib    = (float*)alloc((size_t)TT*NB*384*4);
  (void)ws_size; (void)in_sizes; (void)n_in; (void)out_size;

  const int M = MTOT;                       // 40000
  const int GX = (M + 127)/128;             // 313

  hipMemsetAsync(counts, 0, (size_t)TT*NN*4, stream);
  hist_kernel   <<<(TT*EE)/256, 256, 0, stream>>>(eidx, counts);
  scan_kernel   <<<TT, 256, 0, stream>>>(counts, rp, cursor);
  scatter_kernel<<<(TT*EE)/256, 256, 0, stream>>>(eidx, cursor, ssrc);

  for (int t = 0; t < TT; ++t){
    const int* rpt = rp + t*(NN+1);
    const int* st  = ssrc + (size_t)t*EE;
    // layer 1 (GEMM + fused es/ed), A = x_seq slice (row stride 128, b-stride T*N*128)
    gemm_attn_kernel<FIN><<<dim3(GX, 2), 256, 0, stream>>>(
        x_seq + (size_t)t*NN*FIN, nullptr, (size_t)TT*NN*FIN, W1, a_s1, a_d1, H, es, ed, M);
    agg_kernel<<<dim3(NN, NB*2), 128, 0, stream>>>(H, es, ed, rpt, st, b1, X1, 1);
    // layer 2: A in head-split layout (A0=head0 region, A1=head1 region)
    gemm_attn_kernel<DMODEL><<<dim3(GX, 2), 256, 0, stream>>>(
        X1, X1 + (size_t)M*128, (size_t)NN*128, W2, a_s2, a_d2, H, es, ed, M);
    agg_kernel<<<dim3(NN, NB*2), 128, 0, stream>>>(H, es, ed, rpt, st, b2, X1, 0);
    // pool
    pool1_kernel<<<NB*PCH, 256, 0, stream>>>(X1, part);
    pool2_kernel<<<NB, 256, 0, stream>>>(part, pooled, t);
  }
  gi_kernel <<<TT*NB, 384, 0, stream>>>(pooled, Wih, bih, gib);
  rec_kernel<<<NB, 384, 0, stream>>>(gib, Whh, bhh, Wc, bc, outp);
}

// Round 7
// 3894.287 us; speedup vs baseline: 1.2485x; 1.0818x over previous
//
#include <hip/hip_runtime.h>
#include <cstdint>

#define NB 4       // batch
#define TT 8       // timesteps
#define NN 10000   // nodes
#define FIN 128
#define HID 128
#define EE 320000  // edges per timestep (before self-loops)
#define DMODEL 256 // HEADS*HID
#define MTOT (NB*NN)
#define NEG 0.2f

__device__ __forceinline__ float leaky(float x){ return x >= 0.f ? x : NEG*x; }

// ---------------- CSR build (counting sort by dst, per t) ----------------
__global__ void hist_kernel(const int* __restrict__ eidx, int* __restrict__ counts){
  int idx = blockIdx.x*256 + threadIdx.x;        // t*EE + e, grid exactly T*E/256
  int t = idx / EE, e = idx - t*EE;
  int dst = eidx[(size_t)t*2*EE + EE + e];
  atomicAdd(&counts[t*NN + dst], 1);
}

__global__ void scan_kernel(const int* __restrict__ counts, int* __restrict__ rp,
                            int* __restrict__ cursor){
  int t = blockIdx.x; int tid = threadIdx.x;
  __shared__ int lds[256];
  const int CH = 40;                              // ceil(10000/256)
  int lo = tid*CH, hi = lo+CH < NN ? lo+CH : NN;
  int s = 0;
  for (int i = lo; i < hi; ++i) s += counts[t*NN + i];
  lds[tid] = s; __syncthreads();
  for (int off = 1; off < 256; off <<= 1){
    int v = (tid >= off) ? lds[tid-off] : 0; __syncthreads();
    lds[tid] += v; __syncthreads();
  }
  int run = (tid == 0) ? 0 : lds[tid-1];
  for (int i = lo; i < hi; ++i){
    rp[t*(NN+1) + i] = run; cursor[t*NN + i] = run; run += counts[t*NN + i];
  }
  if (tid == 255) rp[t*(NN+1) + NN] = lds[255];
}

__global__ void scatter_kernel(const int* __restrict__ eidx, int* __restrict__ cursor,
                               int* __restrict__ ssrc){
  int idx = blockIdx.x*256 + threadIdx.x;
  int t = idx / EE, e = idx - t*EE;
  int src = eidx[(size_t)t*2*EE + e];
  int dst = eidx[(size_t)t*2*EE + EE + e];
  int pos = atomicAdd(&cursor[t*NN + dst], 1);
  ssrc[(size_t)t*EE + pos] = src;
}

// ------- fp32 GEMM 128x128 tile, 8x8 microtile, fused es/ed epilogue -------
// Output in HEAD-SPLIT layout: C[head][r][128] (r = b*NN+n), es/ed[head][r].
// A input: K==128 -> rows at A0 + b*bstride + n*128;
//          K==256 -> split halves: A0[r][128] (k<128), A1[r][128] (k>=128).
template<int K>
__global__ __launch_bounds__(256) void gemm_attn_kernel(const float* __restrict__ A0,
    const float* __restrict__ A1, size_t bstride,
    const float* __restrict__ W, const float* __restrict__ av_s, const float* __restrict__ av_d,
    float* __restrict__ C, float* __restrict__ es, float* __restrict__ ed, int M){
  __shared__ float As[16][132];   // transposed A tile (k, row), padded
  __shared__ float Bs[16][128];   // (k, col)
  int tid = threadIdx.x;
  int r0 = blockIdx.x*128, c0 = blockIdx.y*128;
  int ty = tid >> 4, tx = tid & 15;

  // A loader: 128 rows; this thread loads rows (tid>>2) and (tid>>2)+64, f4 slot tid&3
  int cq = (tid & 3)*4;
  const float* a0r0; const float* a0r1; const float* a1r0 = nullptr; const float* a1r1 = nullptr;
  {
    int r_ = r0 + (tid >> 2); if (r_ >= M) r_ = M-1;
    int b = r_/NN, n = r_ - b*NN;
    a0r0 = A0 + (size_t)b*bstride + (size_t)n*128 + cq;
    if (K > 128) a1r0 = A1 + (size_t)r_*128 + cq;
    r_ = r0 + 64 + (tid >> 2); if (r_ >= M) r_ = M-1;
    b = r_/NN; n = r_ - b*NN;
    a0r1 = A0 + (size_t)b*bstride + (size_t)n*128 + cq;
    if (K > 128) a1r1 = A1 + (size_t)r_*128 + cq;
  }
  // B loader: 16 k-rows x 32 f4 (absolute k indexing, W contiguous [K][256])
  const float* brow0 = W + (size_t)(tid>>5)*DMODEL + c0 + (tid & 31)*4;
  const float* brow1 = W + (size_t)((tid>>5)+8)*DMODEL + c0 + (tid & 31)*4;

  float acc[8][8];
  #pragma unroll
  for (int i = 0; i < 8; ++i)
    #pragma unroll
    for (int j = 0; j < 8; ++j) acc[i][j] = 0.f;

  int r_loc = tid >> 2;
  #pragma unroll 1
  for (int half = 0; half < K/128; ++half){
    const float* pr0 = half ? a1r0 : a0r0;
    const float* pr1 = half ? a1r1 : a0r1;
    #pragma unroll 1
    for (int k0 = 0; k0 < 128; k0 += 16){
      int kab = half*128 + k0;
      float4 a0v = *(const float4*)(pr0 + k0);
      float4 a1v = *(const float4*)(pr1 + k0);
      float4 b0v = *(const float4*)(brow0 + (size_t)kab*DMODEL);
      float4 b1v = *(const float4*)(brow1 + (size_t)kab*DMODEL);
      __syncthreads();               // previous iteration done reading LDS
      As[cq+0][r_loc] = a0v.x; As[cq+1][r_loc] = a0v.y; As[cq+2][r_loc] = a0v.z; As[cq+3][r_loc] = a0v.w;
      As[cq+0][64+r_loc] = a1v.x; As[cq+1][64+r_loc] = a1v.y; As[cq+2][64+r_loc] = a1v.z; As[cq+3][64+r_loc] = a1v.w;
      *(float4*)&Bs[tid>>5][(tid&31)*4]     = b0v;
      *(float4*)&Bs[(tid>>5)+8][(tid&31)*4] = b1v;
      __syncthreads();
      #pragma unroll
      for (int kk = 0; kk < 16; ++kk){
        float4 aA = *(const float4*)&As[kk][ty*4];
        float4 aB = *(const float4*)&As[kk][64+ty*4];
        float4 bA = *(const float4*)&Bs[kk][tx*4];
        float4 bB = *(const float4*)&Bs[kk][64+tx*4];
        float ar[8] = {aA.x,aA.y,aA.z,aA.w,aB.x,aB.y,aB.z,aB.w};
        float br[8] = {bA.x,bA.y,bA.z,bA.w,bB.x,bB.y,bB.z,bB.w};
        #pragma unroll
        for (int i = 0; i < 8; ++i)
          #pragma unroll
          for (int j = 0; j < 8; ++j) acc[i][j] += ar[i]*br[j];
      }
    }
  }

  // attention-vector values for this thread's 8 columns (head == c0>>7)
  float as_c[8], ad_c[8];
  #pragma unroll
  for (int j = 0; j < 8; ++j){
    int c = c0 + (j < 4 ? tx*4+j : 64+tx*4+(j-4));
    as_c[j] = av_s[c]; ad_c[j] = av_d[c];
  }
  int hsel = c0 >> 7;
  float* Ch = C + (size_t)hsel*M*128;
  #pragma unroll
  for (int ii = 0; ii < 8; ++ii){
    int r = r0 + (ii < 4 ? ty*4+ii : 64+ty*4+(ii-4));
    float ls = 0.f, ld_ = 0.f;
    #pragma unroll
    for (int j = 0; j < 8; ++j){ ls += acc[ii][j]*as_c[j]; ld_ += acc[ii][j]*ad_c[j]; }
    #pragma unroll
    for (int o = 8; o > 0; o >>= 1){ ls += __shfl_down(ls, o); ld_ += __shfl_down(ld_, o); }
    if (r < M){
      if (tx == 0){ es[(size_t)hsel*M + r] = ls; ed[(size_t)hsel*M + r] = ld_; }
      *(float4*)&Ch[(size_t)r*128 + tx*4]      = make_float4(acc[ii][0],acc[ii][1],acc[ii][2],acc[ii][3]);
      *(float4*)&Ch[(size_t)r*128 + 64 + tx*4] = make_float4(acc[ii][4],acc[ii][5],acc[ii][6],acc[ii][7]);
    }
  }
}

// ------- GAT edge-softmax aggregation, XCD-pinned phases, online softmax -------
// Grid: 8*NN blocks; phase = blockIdx.x & 7 (-> XCD via round-robin), d = blockIdx.x >> 3.
// H/out layout [head][b*NN+n][128]; es/ed layout [head][b*NN+n].
__global__ __launch_bounds__(128) void agg_kernel(const float* __restrict__ H,
    const float* __restrict__ es, const float* __restrict__ ed,
    const int* __restrict__ rp, const int* __restrict__ ssrc,
    const float* __restrict__ bias, float* __restrict__ out, int do_relu){
  int bid = blockIdx.x;
  int ph = bid & 7;          // phase -> XCD (round-robin heuristic; perf-only assumption)
  int d  = bid >> 3;
  int h = ph & 1, b = ph >> 1;
  int tid = threadIdx.x;
  const size_t reg = (size_t)h*MTOT + (size_t)b*NN;   // row offset of this (h,b) region
  const float* esh = es + reg;
  const float* edh = ed + reg;
  const float* Hh  = H + reg*128;
  int e0 = rp[d], e1 = rp[d+1];
  __shared__ float smm[2], sss[2];
  __shared__ float sbc2[2];        // m, inv
  __shared__ float vcache[128];
  __shared__ unsigned int offs[128];
  __shared__ float lal[128];

  float edv  = edh[d];
  float self = leaky(esh[d] + edv);

  // pass 1: single gather + per-lane online (m, sum)
  float m = -1e30f, ssum = 0.f;
  for (int e = e0 + tid; e < e1; e += 128){
    int s = ssrc[e];
    float v = leaky(esh[s] + edv);
    if (e - e0 < 128){ vcache[tid] = v; offs[tid] = (unsigned int)(s*512); }
    float mn = fmaxf(m, v);
    ssum = ssum*expf(m - mn) + expf(v - mn);
    m = mn;
  }
  // wave-level merge (64 lanes)
  #pragma unroll
  for (int o = 32; o > 0; o >>= 1){
    float m2 = __shfl_down(m, o);
    float s2 = __shfl_down(ssum, o);
    float mn = fmaxf(m, m2);
    ssum = ssum*expf(m - mn) + s2*expf(m2 - mn);
    m = mn;
  }
  int w = tid >> 6, lane = tid & 63;
  if (lane == 0){ smm[w] = m; sss[w] = ssum; }
  __syncthreads();
  if (tid == 0){
    float mA = smm[0], sA = sss[0], mB = smm[1], sB = sss[1];
    float mn = fmaxf(fmaxf(mA, mB), self);
    float st = sA*expf(mA - mn) + sB*expf(mB - mn) + expf(self - mn);
    sbc2[0] = mn; sbc2[1] = 1.f/st;
  }
  __syncthreads();
  m = sbc2[0];
  float inv = sbc2[1];

  // pass 2: weighted aggregation; thread = channel (128 per head)
  float acc = expf(self - m) * inv * Hh[(size_t)d*128 + tid];
  const char* Hb = (const char*)Hh + (size_t)tid*4;
  for (int ch = e0; ch < e1; ch += 128){
    int nc = (e1 - ch < 128) ? (e1 - ch) : 128;
    __syncthreads();
    if (tid < nc){
      if (ch == e0){
        lal[tid] = expf(vcache[tid] - m) * inv;      // offs already set in pass 1
      } else {
        int s = ssrc[ch + tid];
        offs[tid] = (unsigned int)(s*512);
        lal[tid]  = expf(leaky(esh[s] + edv) - m) * inv;
      }
    }
    __syncthreads();
    int i = 0;
    float a0 = 0.f, a1 = 0.f, a2 = 0.f, a3 = 0.f;
    for (; i + 4 <= nc; i += 4){
      a0 += lal[i+0] * *(const float*)(Hb + offs[i+0]);
      a1 += lal[i+1] * *(const float*)(Hb + offs[i+1]);
      a2 += lal[i+2] * *(const float*)(Hb + offs[i+2]);
      a3 += lal[i+3] * *(const float*)(Hb + offs[i+3]);
    }
    for (; i < nc; ++i) a0 += lal[i] * *(const float*)(Hb + offs[i]);
    acc += (a0 + a1) + (a2 + a3);
  }
  acc += bias[h*128 + tid];
  if (do_relu) acc = fmaxf(acc, 0.f);
  out[(reg + d)*128 + tid] = acc;
}

// ---------------- node mean-pool (reads head-split layout) ----------------
#define PCH 64
__global__ void pool1_kernel(const float* __restrict__ X2, float* __restrict__ part){
  int b = blockIdx.x / PCH; int ch = blockIdx.x % PCH; int c = threadIdx.x;
  const int RPC = (NN + PCH - 1) / PCH;  // 157
  int d0 = ch*RPC, d1 = d0+RPC < NN ? d0+RPC : NN;
  int hreg = c >> 7, cw = c & 127;
  const float* Xr = X2 + ((size_t)hreg*MTOT + (size_t)b*NN)*128 + cw;
  float s = 0.f;
  for (int d = d0; d < d1; ++d) s += Xr[(size_t)d*128];
  part[(size_t)blockIdx.x*DMODEL + c] = s;
}
__global__ void pool2_kernel(const float* __restrict__ part, float* __restrict__ pooled, int t){
  int b = blockIdx.x; int c = threadIdx.x;
  float s = 0.f;
  for (int ch = 0; ch < PCH; ++ch) s += part[(size_t)(b*PCH + ch)*DMODEL + c];
  pooled[(size_t)(t*NB + b)*DMODEL + c] = s * (1.f/NN);
}

// ---------------- GRU: parallel gi precompute + LDS-resident recurrence ----------------
__global__ __launch_bounds__(384) void gi_kernel(const float* __restrict__ pooled,
    const float* __restrict__ Wih, const float* __restrict__ bih, float* __restrict__ gi){
  int row = blockIdx.x; int j = threadIdx.x;
  __shared__ float xs[256];
  if (j < 256) xs[j] = pooled[(size_t)row*DMODEL + j];
  __syncthreads();
  const float4* Wr = (const float4*)(Wih + (size_t)j*DMODEL);
  float s = bih[j];
  #pragma unroll 8
  for (int k = 0; k < 64; ++k){
    float4 wv = Wr[k];
    s += wv.x*xs[k*4] + wv.y*xs[k*4+1] + wv.z*xs[k*4+2] + wv.w*xs[k*4+3];
  }
  gi[(size_t)row*384 + j] = s;
}

__global__ __launch_bounds__(384) void rec_kernel(const float* __restrict__ gi,
    const float* __restrict__ Whh, const float* __restrict__ bhh,
    const float* __restrict__ Wc, const float* __restrict__ bc, float* __restrict__ outp){
  int b = blockIdx.x; int j = threadIdx.x;
  __shared__ float hs[128], ghs[384], fin[128];
  if (j < 128) hs[j] = 0.f;
  float macc = 0.f;
  const float4* Ur = (const float4*)(Whh + (size_t)j*HID);
  float bh = bhh[j];
  for (int t = 0; t < TT; ++t){
    __syncthreads();                       // hs ready
    float s = bh;
    #pragma unroll 8
    for (int k = 0; k < 32; ++k){
      float4 wv = Ur[k];
      s += wv.x*hs[k*4] + wv.y*hs[k*4+1] + wv.z*hs[k*4+2] + wv.w*hs[k*4+3];
    }
    ghs[j] = s; __syncthreads();
    float hnew = 0.f;
    if (j < 128){
      const float* g = gi + (size_t)(t*NB + b)*384;
      float r = 1.f/(1.f + expf(-(g[j] + ghs[j])));
      float z = 1.f/(1.f + expf(-(g[128+j] + ghs[128+j])));
      float n = tanhf(g[256+j] + r*ghs[256+j]);
      hnew = (1.f - z)*n + z*hs[j];
    }
    __syncthreads();
    if (j < 128){ hs[j] = hnew; macc += hnew; }
  }
  if (j < 128) fin[j] = macc * (1.f/TT);
  __syncthreads();
  if (j < 10){
    float s = bc[j];
    for (int k = 0; k < 128; ++k) s += fin[k]*Wc[k*10 + j];
    outp[b*10 + j] = s;
  }
}

// ---------------- launch ----------------
extern "C" void kernel_launch(void* const* d_in, const int* in_sizes, int n_in,
                              void* d_out, int out_size, void* d_ws, size_t ws_size,
                              hipStream_t stream){
  const float* x_seq = (const float*)d_in[0];
  const int*   eidx  = (const int*)d_in[1];
  const float* W1    = (const float*)d_in[2];
  const float* a_s1  = (const float*)d_in[3];
  const float* a_d1  = (const float*)d_in[4];
  const float* b1    = (const float*)d_in[5];
  const float* W2    = (const float*)d_in[6];
  const float* a_s2  = (const float*)d_in[7];
  const float* a_d2  = (const float*)d_in[8];
  const float* b2    = (const float*)d_in[9];
  const float* Wih   = (const float*)d_in[10];
  const float* Whh   = (const float*)d_in[11];
  const float* bih   = (const float*)d_in[12];
  const float* bhh   = (const float*)d_in[13];
  const float* Wc    = (const float*)d_in[14];
  const float* bc    = (const float*)d_in[15];
  float* outp = (float*)d_out;

  char* ws = (char*)d_ws;
  size_t off = 0;
  auto alloc = [&](size_t bytes)->char*{
    char* p = ws + off; off += (bytes + 511) & ~(size_t)511; return p;
  };
  int*   counts = (int*)  alloc((size_t)TT*NN*4);
  int*   rp     = (int*)  alloc((size_t)TT*(NN+1)*4);
  int*   cursor = (int*)  alloc((size_t)TT*NN*4);
  int*   ssrc   = (int*)  alloc((size_t)TT*EE*4);
  float* H      = (float*)alloc((size_t)MTOT*DMODEL*4);   // [head][M][128]
  float* X1     = (float*)alloc((size_t)MTOT*DMODEL*4);   // [head][M][128]
  float* es     = (float*)alloc((size_t)2*MTOT*4);        // [head][M]
  float* ed     = (float*)alloc((size_t)2*MTOT*4);
  float* part   = (float*)alloc((size_t)NB*PCH*DMODEL*4);
  float* pooled = (float*)alloc((size_t)TT*NB*DMODEL*4);
  float* gib    = (float*)alloc((size_t)TT*NB*384*4);
  (void)ws_size; (void)in_sizes; (void)n_in; (void)out_size;

  const int M = MTOT;                       // 40000
  const int GX = (M + 127)/128;             // 313

  hipMemsetAsync(counts, 0, (size_t)TT*NN*4, stream);
  hist_kernel   <<<(TT*EE)/256, 256, 0, stream>>>(eidx, counts);
  scan_kernel   <<<TT, 256, 0, stream>>>(counts, rp, cursor);
  scatter_kernel<<<(TT*EE)/256, 256, 0, stream>>>(eidx, cursor, ssrc);

  for (int t = 0; t < TT; ++t){
    const int* rpt = rp + t*(NN+1);
    const int* st  = ssrc + (size_t)t*EE;
    // layer 1 (GEMM + fused es/ed), A = x_seq slice (row stride 128, b-stride T*N*128)
    gemm_attn_kernel<FIN><<<dim3(GX, 2), 256, 0, stream>>>(
        x_seq + (size_t)t*NN*FIN, nullptr, (size_t)TT*NN*FIN, W1, a_s1, a_d1, H, es, ed, M);
    agg_kernel<<<8*NN, 128, 0, stream>>>(H, es, ed, rpt, st, b1, X1, 1);
    // layer 2: A in head-split layout (A0=head0 region, A1=head1 region)
    gemm_attn_kernel<DMODEL><<<dim3(GX, 2), 256, 0, stream>>>(
        X1, X1 + (size_t)M*128, (size_t)NN*128, W2, a_s2, a_d2, H, es, ed, M);
    agg_kernel<<<8*NN, 128, 0, stream>>>(H, es, ed, rpt, st, b2, X1, 0);
    // pool
    pool1_kernel<<<NB*PCH, 256, 0, stream>>>(X1, part);
    pool2_kernel<<<NB, 256, 0, stream>>>(part, pooled, t);
  }
  gi_kernel <<<TT*NB, 384, 0, stream>>>(pooled, Wih, bih, gib);
  rec_kernel<<<NB, 384, 0, stream>>>(gib, Whh, bhh, Wc, bc, outp);
}

// Round 8
// 3393.176 us; speedup vs baseline: 1.4329x; 1.1477x over previous
//
#include <hip/hip_runtime.h>
#include <cstdint>

#define NB 4       // batch
#define TT 8       // timesteps
#define NN 10000   // nodes
#define FIN 128
#define HID 128
#define EE 320000  // edges per timestep (before self-loops)
#define DMODEL 256 // HEADS*HID
#define MTOT (NB*NN)
#define NEG 0.2f

__device__ __forceinline__ float leaky(float x){ return x >= 0.f ? x : NEG*x; }

// ---------------- CSR build (counting sort by dst, per t) ----------------
__global__ void hist_kernel(const int* __restrict__ eidx, int* __restrict__ counts){
  int idx = blockIdx.x*256 + threadIdx.x;        // t*EE + e, grid exactly T*E/256
  int t = idx / EE, e = idx - t*EE;
  int dst = eidx[(size_t)t*2*EE + EE + e];
  atomicAdd(&counts[t*NN + dst], 1);
}

__global__ void scan_kernel(const int* __restrict__ counts, int* __restrict__ rp,
                            int* __restrict__ cursor){
  int t = blockIdx.x; int tid = threadIdx.x;
  __shared__ int lds[256];
  const int CH = 40;                              // ceil(10000/256)
  int lo = tid*CH, hi = lo+CH < NN ? lo+CH : NN;
  int s = 0;
  for (int i = lo; i < hi; ++i) s += counts[t*NN + i];
  lds[tid] = s; __syncthreads();
  for (int off = 1; off < 256; off <<= 1){
    int v = (tid >= off) ? lds[tid-off] : 0; __syncthreads();
    lds[tid] += v; __syncthreads();
  }
  int run = (tid == 0) ? 0 : lds[tid-1];
  for (int i = lo; i < hi; ++i){
    rp[t*(NN+1) + i] = run; cursor[t*NN + i] = run; run += counts[t*NN + i];
  }
  if (tid == 255) rp[t*(NN+1) + NN] = lds[255];
}

__global__ void scatter_kernel(const int* __restrict__ eidx, int* __restrict__ cursor,
                               int* __restrict__ ssrc){
  int idx = blockIdx.x*256 + threadIdx.x;
  int t = idx / EE, e = idx - t*EE;
  int src = eidx[(size_t)t*2*EE + e];
  int dst = eidx[(size_t)t*2*EE + EE + e];
  int pos = atomicAdd(&cursor[t*NN + dst], 1);
  ssrc[(size_t)t*EE + pos] = src;
}

// ------- fp32 GEMM 128x128 tile, 8x8 microtile, fused es/ed epilogue -------
// Output in HEAD-SPLIT layout: C[head][r][128] (r = b*NN+n), es/ed[head][r].
// A input: K==128 -> rows at A0 + b*bstride + n*128;
//          K==256 -> split halves: A0[r][128] (k<128), A1[r][128] (k>=128).
template<int K>
__global__ __launch_bounds__(256) void gemm_attn_kernel(const float* __restrict__ A0,
    const float* __restrict__ A1, size_t bstride,
    const float* __restrict__ W, const float* __restrict__ av_s, const float* __restrict__ av_d,
    float* __restrict__ C, float* __restrict__ es, float* __restrict__ ed, int M){
  __shared__ float As[16][132];   // transposed A tile (k, row), padded
  __shared__ float Bs[16][128];   // (k, col)
  int tid = threadIdx.x;
  int r0 = blockIdx.x*128, c0 = blockIdx.y*128;
  int ty = tid >> 4, tx = tid & 15;

  // A loader: 128 rows; this thread loads rows (tid>>2) and (tid>>2)+64, f4 slot tid&3
  int cq = (tid & 3)*4;
  const float* a0r0; const float* a0r1; const float* a1r0 = nullptr; const float* a1r1 = nullptr;
  {
    int r_ = r0 + (tid >> 2); if (r_ >= M) r_ = M-1;
    int b = r_/NN, n = r_ - b*NN;
    a0r0 = A0 + (size_t)b*bstride + (size_t)n*128 + cq;
    if (K > 128) a1r0 = A1 + (size_t)r_*128 + cq;
    r_ = r0 + 64 + (tid >> 2); if (r_ >= M) r_ = M-1;
    b = r_/NN; n = r_ - b*NN;
    a0r1 = A0 + (size_t)b*bstride + (size_t)n*128 + cq;
    if (K > 128) a1r1 = A1 + (size_t)r_*128 + cq;
  }
  // B loader: 16 k-rows x 32 f4 (absolute k indexing, W contiguous [K][256])
  const float* brow0 = W + (size_t)(tid>>5)*DMODEL + c0 + (tid & 31)*4;
  const float* brow1 = W + (size_t)((tid>>5)+8)*DMODEL + c0 + (tid & 31)*4;

  float acc[8][8];
  #pragma unroll
  for (int i = 0; i < 8; ++i)
    #pragma unroll
    for (int j = 0; j < 8; ++j) acc[i][j] = 0.f;

  int r_loc = tid >> 2;
  #pragma unroll 1
  for (int half = 0; half < K/128; ++half){
    const float* pr0 = half ? a1r0 : a0r0;
    const float* pr1 = half ? a1r1 : a0r1;
    #pragma unroll 1
    for (int k0 = 0; k0 < 128; k0 += 16){
      int kab = half*128 + k0;
      float4 a0v = *(const float4*)(pr0 + k0);
      float4 a1v = *(const float4*)(pr1 + k0);
      float4 b0v = *(const float4*)(brow0 + (size_t)kab*DMODEL);
      float4 b1v = *(const float4*)(brow1 + (size_t)kab*DMODEL);
      __syncthreads();               // previous iteration done reading LDS
      As[cq+0][r_loc] = a0v.x; As[cq+1][r_loc] = a0v.y; As[cq+2][r_loc] = a0v.z; As[cq+3][r_loc] = a0v.w;
      As[cq+0][64+r_loc] = a1v.x; As[cq+1][64+r_loc] = a1v.y; As[cq+2][64+r_loc] = a1v.z; As[cq+3][64+r_loc] = a1v.w;
      *(float4*)&Bs[tid>>5][(tid&31)*4]     = b0v;
      *(float4*)&Bs[(tid>>5)+8][(tid&31)*4] = b1v;
      __syncthreads();
      #pragma unroll
      for (int kk = 0; kk < 16; ++kk){
        float4 aA = *(const float4*)&As[kk][ty*4];
        float4 aB = *(const float4*)&As[kk][64+ty*4];
        float4 bA = *(const float4*)&Bs[kk][tx*4];
        float4 bB = *(const float4*)&Bs[kk][64+tx*4];
        float ar[8] = {aA.x,aA.y,aA.z,aA.w,aB.x,aB.y,aB.z,aB.w};
        float br[8] = {bA.x,bA.y,bA.z,bA.w,bB.x,bB.y,bB.z,bB.w};
        #pragma unroll
        for (int i = 0; i < 8; ++i)
          #pragma unroll
          for (int j = 0; j < 8; ++j) acc[i][j] += ar[i]*br[j];
      }
    }
  }

  // attention-vector values for this thread's 8 columns (head == c0>>7)
  float as_c[8], ad_c[8];
  #pragma unroll
  for (int j = 0; j < 8; ++j){
    int c = c0 + (j < 4 ? tx*4+j : 64+tx*4+(j-4));
    as_c[j] = av_s[c]; ad_c[j] = av_d[c];
  }
  int hsel = c0 >> 7;
  float* Ch = C + (size_t)hsel*M*128;
  #pragma unroll
  for (int ii = 0; ii < 8; ++ii){
    int r = r0 + (ii < 4 ? ty*4+ii : 64+ty*4+(ii-4));
    float ls = 0.f, ld_ = 0.f;
    #pragma unroll
    for (int j = 0; j < 8; ++j){ ls += acc[ii][j]*as_c[j]; ld_ += acc[ii][j]*ad_c[j]; }
    #pragma unroll
    for (int o = 8; o > 0; o >>= 1){ ls += __shfl_down(ls, o); ld_ += __shfl_down(ld_, o); }
    if (r < M){
      if (tx == 0){ es[(size_t)hsel*M + r] = ls; ed[(size_t)hsel*M + r] = ld_; }
      *(float4*)&Ch[(size_t)r*128 + tx*4]      = make_float4(acc[ii][0],acc[ii][1],acc[ii][2],acc[ii][3]);
      *(float4*)&Ch[(size_t)r*128 + 64 + tx*4] = make_float4(acc[ii][4],acc[ii][5],acc[ii][6],acc[ii][7]);
    }
  }
}

// ------- GAT edge-softmax aggregation, XCD-pinned phases -------
// Grid: 8*NN blocks; phase = blockIdx.x & 7 (-> XCD via round-robin), d = blockIdx.x >> 3.
// Single exp per edge: max pass is exp-free (vcache), alpha = p*inv reused from sum pass.
// Pass 3: 32-lane float4 gather per edge, 4 edge-quarters, LDS quarter-reduce.
__global__ __launch_bounds__(128) void agg_kernel(const float* __restrict__ H,
    const float* __restrict__ es, const float* __restrict__ ed,
    const int* __restrict__ rp, const int* __restrict__ ssrc,
    const float* __restrict__ bias, float* __restrict__ out, int do_relu){
  int bid = blockIdx.x;
  int ph = bid & 7;          // phase -> XCD (round-robin heuristic; perf-only assumption)
  int d  = bid >> 3;
  int h = ph & 1, b = ph >> 1;
  int tid = threadIdx.x;
  const size_t reg = (size_t)h*MTOT + (size_t)b*NN;   // row offset of this (h,b) region
  const float* esh = es + reg;
  const float* edh = ed + reg;
  const float* Hh  = H + reg*128;
  int e0 = rp[d], e1 = rp[d+1];
  int deg = e1 - e0;
  int nc0 = deg < 128 ? deg : 128;
  __shared__ float sred[2];
  __shared__ float sbc2[2];        // m, inv
  __shared__ float vcache[128];
  __shared__ unsigned int offsc[128];
  __shared__ float2 lalf2[128];    // (alpha, byte-offset bits)
  __shared__ float4 sacc[128];

  float edv  = edh[d];
  float self = leaky(esh[d] + edv);
  int w = tid >> 6, lane = tid & 63;

  // pass 1: gather + cache chunk 0, pure max reduce (no exp)
  float m = self;
  for (int e = e0 + tid; e < e1; e += 128){
    int s = ssrc[e];
    float v = leaky(esh[s] + edv);
    if (e - e0 < 128){ vcache[tid] = v; offsc[tid] = (unsigned int)(s*512); }
    m = fmaxf(m, v);
  }
  #pragma unroll
  for (int o = 32; o > 0; o >>= 1) m = fmaxf(m, __shfl_down(m, o));
  if (lane == 0) sred[w] = m;
  __syncthreads();
  if (tid == 0) sbc2[0] = fmaxf(sred[0], sred[1]);
  __syncthreads();
  m = sbc2[0];

  // pass 2: p = exp(v-m) for chunk 0 (reused as alpha), block-sum for denom
  float p = 0.f;
  if (tid < nc0) p = expf(vcache[tid] - m);
  float ssum = p;
  for (int e = e0 + 128 + tid; e < e1; e += 128)
    ssum += expf(leaky(esh[ssrc[e]] + edv) - m);
  #pragma unroll
  for (int o = 32; o > 0; o >>= 1) ssum += __shfl_down(ssum, o);
  if (lane == 0) sred[w] = ssum;
  __syncthreads();
  if (tid == 0) sbc2[1] = 1.f/(sred[0] + sred[1] + expf(self - m));
  __syncthreads();
  float inv = sbc2[1];
  if (tid < nc0) lalf2[tid] = make_float2(p*inv, __uint_as_float(offsc[tid]));
  __syncthreads();

  // pass 3: quarter-split float4 gather; q = edge-slot, c = channel-group
  int q = tid >> 5, c = tid & 31;
  const char* Hbase = (const char*)Hh;
  unsigned cb = (unsigned)(c*16);
  float4 accA = make_float4(0.f,0.f,0.f,0.f);
  float4 accB = make_float4(0.f,0.f,0.f,0.f);
  for (int ch = e0; ch < e1; ch += 128){
    int nc = (e1 - ch < 128) ? (e1 - ch) : 128;
    if (ch > e0){
      __syncthreads();               // previous chunk fully consumed
      if (tid < nc){
        int s = ssrc[ch + tid];
        lalf2[tid] = make_float2(expf(leaky(esh[s] + edv) - m)*inv,
                                 __uint_as_float((unsigned int)(s*512)));
      }
      __syncthreads();
    }
    int i = q;
    for (; i + 4 < nc; i += 8){
      float2 l0 = lalf2[i];
      float2 l1 = lalf2[i+4];
      float4 h0 = *(const float4*)(Hbase + (__float_as_uint(l0.y) + cb));
      float4 h1 = *(const float4*)(Hbase + (__float_as_uint(l1.y) + cb));
      accA.x += l0.x*h0.x; accA.y += l0.x*h0.y; accA.z += l0.x*h0.z; accA.w += l0.x*h0.w;
      accB.x += l1.x*h1.x; accB.y += l1.x*h1.y; accB.z += l1.x*h1.z; accB.w += l1.x*h1.w;
    }
    if (i < nc){
      float2 l0 = lalf2[i];
      float4 h0 = *(const float4*)(Hbase + (__float_as_uint(l0.y) + cb));
      accA.x += l0.x*h0.x; accA.y += l0.x*h0.y; accA.z += l0.x*h0.z; accA.w += l0.x*h0.w;
    }
  }
  accA.x += accB.x; accA.y += accB.y; accA.z += accB.z; accA.w += accB.w;
  __syncthreads();
  sacc[tid] = accA;
  __syncthreads();
  if (tid < 32){
    float4 r0 = sacc[tid], r1 = sacc[tid+32], r2 = sacc[tid+64], r3 = sacc[tid+96];
    float4 r = make_float4(r0.x+r1.x+r2.x+r3.x, r0.y+r1.y+r2.y+r3.y,
                           r0.z+r1.z+r2.z+r3.z, r0.w+r1.w+r2.w+r3.w);
    float sw = expf(self - m)*inv;
    float4 hd = *(const float4*)(Hbase + (size_t)d*512 + tid*16);
    float4 bv = *(const float4*)(bias + h*128 + tid*4);
    r.x += sw*hd.x + bv.x; r.y += sw*hd.y + bv.y;
    r.z += sw*hd.z + bv.z; r.w += sw*hd.w + bv.w;
    if (do_relu){
      r.x = fmaxf(r.x, 0.f); r.y = fmaxf(r.y, 0.f);
      r.z = fmaxf(r.z, 0.f); r.w = fmaxf(r.w, 0.f);
    }
    *(float4*)&out[(reg + d)*128 + tid*4] = r;
  }
}

// ---------------- node mean-pool (reads head-split layout) ----------------
#define PCH 64
__global__ void pool1_kernel(const float* __restrict__ X2, float* __restrict__ part){
  int b = blockIdx.x / PCH; int ch = blockIdx.x % PCH; int c = threadIdx.x;
  const int RPC = (NN + PCH - 1) / PCH;  // 157
  int d0 = ch*RPC, d1 = d0+RPC < NN ? d0+RPC : NN;
  int hreg = c >> 7, cw = c & 127;
  const float* Xr = X2 + ((size_t)hreg*MTOT + (size_t)b*NN)*128 + cw;
  float s = 0.f;
  for (int d = d0; d < d1; ++d) s += Xr[(size_t)d*128];
  part[(size_t)blockIdx.x*DMODEL + c] = s;
}
__global__ void pool2_kernel(const float* __restrict__ part, float* __restrict__ pooled, int t){
  int b = blockIdx.x; int c = threadIdx.x;
  float s = 0.f;
  for (int ch = 0; ch < PCH; ++ch) s += part[(size_t)(b*PCH + ch)*DMODEL + c];
  pooled[(size_t)(t*NB + b)*DMODEL + c] = s * (1.f/NN);
}

// ---------------- GRU: parallel gi precompute + LDS-resident recurrence ----------------
__global__ __launch_bounds__(384) void gi_kernel(const float* __restrict__ pooled,
    const float* __restrict__ Wih, const float* __restrict__ bih, float* __restrict__ gi){
  int row = blockIdx.x; int j = threadIdx.x;
  __shared__ float xs[256];
  if (j < 256) xs[j] = pooled[(size_t)row*DMODEL + j];
  __syncthreads();
  const float4* Wr = (const float4*)(Wih + (size_t)j*DMODEL);
  float s = bih[j];
  #pragma unroll 8
  for (int k = 0; k < 64; ++k){
    float4 wv = Wr[k];
    s += wv.x*xs[k*4] + wv.y*xs[k*4+1] + wv.z*xs[k*4+2] + wv.w*xs[k*4+3];
  }
  gi[(size_t)row*384 + j] = s;
}

__global__ __launch_bounds__(384) void rec_kernel(const float* __restrict__ gi,
    const float* __restrict__ Whh, const float* __restrict__ bhh,
    const float* __restrict__ Wc, const float* __restrict__ bc, float* __restrict__ outp){
  int b = blockIdx.x; int j = threadIdx.x;
  __shared__ float hs[128], ghs[384], fin[128];
  if (j < 128) hs[j] = 0.f;
  float macc = 0.f;
  const float4* Ur = (const float4*)(Whh + (size_t)j*HID);
  float bh = bhh[j];
  for (int t = 0; t < TT; ++t){
    __syncthreads();                       // hs ready
    float s = bh;
    #pragma unroll 8
    for (int k = 0; k < 32; ++k){
      float4 wv = Ur[k];
      s += wv.x*hs[k*4] + wv.y*hs[k*4+1] + wv.z*hs[k*4+2] + wv.w*hs[k*4+3];
    }
    ghs[j] = s; __syncthreads();
    float hnew = 0.f;
    if (j < 128){
      const float* g = gi + (size_t)(t*NB + b)*384;
      float r = 1.f/(1.f + expf(-(g[j] + ghs[j])));
      float z = 1.f/(1.f + expf(-(g[128+j] + ghs[128+j])));
      float n = tanhf(g[256+j] + r*ghs[256+j]);
      hnew = (1.f - z)*n + z*hs[j];
    }
    __syncthreads();
    if (j < 128){ hs[j] = hnew; macc += hnew; }
  }
  if (j < 128) fin[j] = macc * (1.f/TT);
  __syncthreads();
  if (j < 10){
    float s = bc[j];
    for (int k = 0; k < 128; ++k) s += fin[k]*Wc[k*10 + j];
    outp[b*10 + j] = s;
  }
}

// ---------------- launch ----------------
extern "C" void kernel_launch(void* const* d_in, const int* in_sizes, int n_in,
                              void* d_out, int out_size, void* d_ws, size_t ws_size,
                              hipStream_t stream){
  const float* x_seq = (const float*)d_in[0];
  const int*   eidx  = (const int*)d_in[1];
  const float* W1    = (const float*)d_in[2];
  const float* a_s1  = (const float*)d_in[3];
  const float* a_d1  = (const float*)d_in[4];
  const float* b1    = (const float*)d_in[5];
  const float* W2    = (const float*)d_in[6];
  const float* a_s2  = (const float*)d_in[7];
  const float* a_d2  = (const float*)d_in[8];
  const float* b2    = (const float*)d_in[9];
  const float* Wih   = (const float*)d_in[10];
  const float* Whh   = (const float*)d_in[11];
  const float* bih   = (const float*)d_in[12];
  const float* bhh   = (const float*)d_in[13];
  const float* Wc    = (const float*)d_in[14];
  const float* bc    = (const float*)d_in[15];
  float* outp = (float*)d_out;

  char* ws = (char*)d_ws;
  size_t off = 0;
  auto alloc = [&](size_t bytes)->char*{
    char* p = ws + off; off += (bytes + 511) & ~(size_t)511; return p;
  };
  int*   counts = (int*)  alloc((size_t)TT*NN*4);
  int*   rp     = (int*)  alloc((size_t)TT*(NN+1)*4);
  int*   cursor = (int*)  alloc((size_t)TT*NN*4);
  int*   ssrc   = (int*)  alloc((size_t)TT*EE*4);
  float* H      = (float*)alloc((size_t)MTOT*DMODEL*4);   // [head][M][128]
  float* X1     = (float*)alloc((size_t)MTOT*DMODEL*4);   // [head][M][128]
  float* es     = (float*)alloc((size_t)2*MTOT*4);        // [head][M]
  float* ed     = (float*)alloc((size_t)2*MTOT*4);
  float* part   = (float*)alloc((size_t)NB*PCH*DMODEL*4);
  float* pooled = (float*)alloc((size_t)TT*NB*DMODEL*4);
  float* gib    = (float*)alloc((size_t)TT*NB*384*4);
  (void)ws_size; (void)in_sizes; (void)n_in; (void)out_size;

  const int M = MTOT;                       // 40000
  const int GX = (M + 127)/128;             // 313

  hipMemsetAsync(counts, 0, (size_t)TT*NN*4, stream);
  hist_kernel   <<<(TT*EE)/256, 256, 0, stream>>>(eidx, counts);
  scan_kernel   <<<TT, 256, 0, stream>>>(counts, rp, cursor);
  scatter_kernel<<<(TT*EE)/256, 256, 0, stream>>>(eidx, cursor, ssrc);

  for (int t = 0; t < TT; ++t){
    const int* rpt = rp + t*(NN+1);
    const int* st  = ssrc + (size_t)t*EE;
    // layer 1 (GEMM + fused es/ed), A = x_seq slice (row stride 128, b-stride T*N*128)
    gemm_attn_kernel<FIN><<<dim3(GX, 2), 256, 0, stream>>>(
        x_seq + (size_t)t*NN*FIN, nullptr, (size_t)TT*NN*FIN, W1, a_s1, a_d1, H, es, ed, M);
    agg_kernel<<<8*NN, 128, 0, stream>>>(H, es, ed, rpt, st, b1, X1, 1);
    // layer 2: A in head-split layout (A0=head0 region, A1=head1 region)
    gemm_attn_kernel<DMODEL><<<dim3(GX, 2), 256, 0, stream>>>(
        X1, X1 + (size_t)M*128, (size_t)NN*128, W2, a_s2, a_d2, H, es, ed, M);
    agg_kernel<<<8*NN, 128, 0, stream>>>(H, es, ed, rpt, st, b2, X1, 0);
    // pool
    pool1_kernel<<<NB*PCH, 256, 0, stream>>>(X1, part);
    pool2_kernel<<<NB, 256, 0, stream>>>(part, pooled, t);
  }
  gi_kernel <<<TT*NB, 384, 0, stream>>>(pooled, Wih, bih, gib);
  rec_kernel<<<NB, 384, 0, stream>>>(gib, Whh, bhh, Wc, bc, outp);
}